// Round 8
// baseline (281.370 us; speedup 1.0000x reference)
//
#include <hip/hip_runtime.h>
#include <math.h>

// ===========================================================================
// CoAtten2: C=1024, H=W=64, HW=4096. Split-bf16 MFMA pipeline (3-term:
// ah*bh + ah*bl + al*bh; final GEMM 2-term with A=probs).
//
// R15 changes vs R14 (R14 CRASHED: (256,4) caps unified regs at 128 but the
// kernel needs ~148 (84 VGPR + 64 acc) -> in-loop spills; spill VMEM breaks
// the hand-counted vmcnt discipline; a spilled address reg reloaded under
// broken waits -> wild pointer -> page fault):
//   - __launch_bounds__(256, 3): budget 512/3 ~= 170 >= 148 -> NO spills,
//     3 blocks/CU resident = 12 waves/CU (vs R13's 8). Single variable.
//   - LESSON: hand-counted vmcnt requires the compiler to emit ZERO VMEM of
//     its own in the counted region -> never cap registers below footprint.
//   - Everything else IDENTICAL to R13 (true counted-vmcnt pipeline, NJ=4
//     geometry, XCD swizzles): absmax must stay exactly 0.015625.
// ===========================================================================

typedef __attribute__((ext_vector_type(8))) short    bf16x8;   // MFMA A/B frag
typedef __attribute__((ext_vector_type(4))) float    f32x4;    // MFMA C/D frag

__device__ __forceinline__ unsigned short f2bf(float x) {
    unsigned u = __float_as_uint(x);
    u += 0x7FFFu + ((u >> 16) & 1u);    // round-to-nearest-even
    return (unsigned short)(u >> 16);
}
__device__ __forceinline__ float bf2f(unsigned short h) {
    return __uint_as_float(((unsigned)h) << 16);
}
__device__ __forceinline__ void split2(float x, unsigned short& h, unsigned short& l) {
    h = f2bf(x);
    l = f2bf(x - bf2f(h));
}

// Frag-major (swizzled) offset for an A-operand matrix [M][K], kpan = K/32.
__device__ __forceinline__ size_t swz(int m, int k, int kpan) {
    return ((size_t)((m >> 4) * kpan + (k >> 5))) * 512
         + (size_t)((((k >> 3) & 3) * 16 + (m & 15)) * 8 + (k & 7));
}

// Async global->LDS DMA, 16B per lane. LDS dest = wave-uniform base + lane*16.
__device__ __forceinline__ void gld16(const unsigned short* g, unsigned short* l) {
    __builtin_amdgcn_global_load_lds(
        (const __attribute__((address_space(1))) unsigned int*)g,
        (__attribute__((address_space(3))) unsigned int*)l,
        16, 0, 0);
}

// 16B global load via inline asm: NOT tracked by the compiler's waitcnt pass.
// Caller is responsible for s_waitcnt vmcnt(N) before reading the result.
__device__ __forceinline__ bf16x8 gload16(const unsigned short* p) {
    bf16x8 r;
    asm volatile("global_load_dwordx4 %0, %1, off"
                 : "=v"(r) : "v"(p) : "memory");
    return r;
}

// Raw workgroup barrier WITHOUT the __syncthreads vmcnt(0) drain.
#define RAW_BARRIER() asm volatile("s_barrier" ::: "memory")

// Exact counted vmem wait: allow N newest ops to stay in flight.
template<int N>
__device__ __forceinline__ void vmwait() {
    asm volatile("s_waitcnt vmcnt(%0)" :: "i"(N) : "memory");
}

// ---------------------------------------------------------------------------
// All-weights split -> SWIZZLED h/l (weights are GEMM-A operands, kpan=32).
__global__ __launch_bounds__(256) void weights_split_k(
    const float* __restrict__ Wq, const float* __restrict__ Wk1,
    const float* __restrict__ Wk2, const float* __restrict__ Wv,
    unsigned short* __restrict__ Wqh, unsigned short* __restrict__ Wql,
    unsigned short* __restrict__ Wk1h, unsigned short* __restrict__ Wk1l,
    unsigned short* __restrict__ Wk2h, unsigned short* __restrict__ Wk2l,
    unsigned short* __restrict__ Wvh, unsigned short* __restrict__ Wvl)
{
    const int gi = blockIdx.x;
    const float* src; unsigned short *H, *L; int base;
    if (gi < 512)       { src = Wq;  H = Wqh;  L = Wql;  base = gi; }
    else if (gi < 1024) { src = Wk1; H = Wk1h; L = Wk1l; base = gi - 512; }
    else if (gi < 1536) { src = Wk2; H = Wk2h; L = Wk2l; base = gi - 1024; }
    else                { src = Wv;  H = Wvh;  L = Wvl;  base = gi - 1536; }
    const size_t i = (size_t)base * 1024 + threadIdx.x * 4;
    const int m = (int)(i >> 10);
    const int k = (int)(i & 1023);
    const float4 v = *(const float4*)(src + i);
    ushort4 h, l;
    split2(v.x, h.x, l.x); split2(v.y, h.y, l.y);
    split2(v.z, h.z, l.z); split2(v.w, h.w, l.w);
    const size_t o = swz(m, k, 32);      // k&7 in {0,4}: 4 elems contiguous
    *(ushort4*)(H + o) = h;
    *(ushort4*)(L + o) = l;
}

// ---------------------------------------------------------------------------
// Transpose + split for the 3 inputs in one launch (z selects which).
__global__ __launch_bounds__(256) void transpose3_k(
    const float* __restrict__ x0, const float* __restrict__ x1,
    const float* __restrict__ x2,
    unsigned short* __restrict__ t0h, unsigned short* __restrict__ t0l,
    unsigned short* __restrict__ t1h, unsigned short* __restrict__ t1l,
    unsigned short* __restrict__ t2h, unsigned short* __restrict__ t2l)
{
    const float* X; unsigned short *Th, *Tl;
    if (blockIdx.z == 0)      { X = x0; Th = t0h; Tl = t0l; }
    else if (blockIdx.z == 1) { X = x1; Th = t1h; Tl = t1l; }
    else                      { X = x2; Th = t2h; Tl = t2l; }

    __shared__ float t[32 * 33];
    const int tid = threadIdx.x;
    const int c0 = blockIdx.y * 32;
    const int p0 = blockIdx.x * 32;

    const int cl = tid >> 3;
    const int p4 = (tid & 7) * 4;
    const float4 v = *(const float4*)(X + (size_t)(c0 + cl) * 4096 + p0 + p4);
    t[(p4 + 0) * 33 + cl] = v.x;
    t[(p4 + 1) * 33 + cl] = v.y;
    t[(p4 + 2) * 33 + cl] = v.z;
    t[(p4 + 3) * 33 + cl] = v.w;
    __syncthreads();

    const int pl = tid >> 3;
    const int c4 = (tid & 7) * 4;
    ushort4 h, l;
    split2(t[pl * 33 + c4 + 0], h.x, l.x);
    split2(t[pl * 33 + c4 + 1], h.y, l.y);
    split2(t[pl * 33 + c4 + 2], h.z, l.z);
    split2(t[pl * 33 + c4 + 3], h.w, l.w);
    const size_t o = (size_t)(p0 + pl) * 1024 + c0 + c4;
    *(ushort4*)(Th + o) = h;
    *(ushort4*)(Tl + o) = l;
}

// Single-matrix transpose+split, row-major output (VT = B of final GEMM).
__global__ __launch_bounds__(256) void transpose1_k(
    const float* __restrict__ X,
    unsigned short* __restrict__ Th, unsigned short* __restrict__ Tl)
{
    __shared__ float t[32 * 33];
    const int tid = threadIdx.x;
    const int c0 = blockIdx.y * 32;
    const int p0 = blockIdx.x * 32;

    const int cl = tid >> 3;
    const int p4 = (tid & 7) * 4;
    const float4 v = *(const float4*)(X + (size_t)(c0 + cl) * 4096 + p0 + p4);
    t[(p4 + 0) * 33 + cl] = v.x;
    t[(p4 + 1) * 33 + cl] = v.y;
    t[(p4 + 2) * 33 + cl] = v.z;
    t[(p4 + 3) * 33 + cl] = v.w;
    __syncthreads();

    const int pl = tid >> 3;
    const int c4 = (tid & 7) * 4;
    ushort4 h, l;
    split2(t[pl * 33 + c4 + 0], h.x, l.x);
    split2(t[pl * 33 + c4 + 1], h.y, l.y);
    split2(t[pl * 33 + c4 + 2], h.z, l.z);
    split2(t[pl * 33 + c4 + 3], h.w, l.w);
    const size_t o = (size_t)(p0 + pl) * 1024 + c0 + c4;
    *(ushort4*)(Th + o) = h;
    *(ushort4*)(Tl + o) = l;
}

// ---------------------------------------------------------------------------
// GEMM core v7: TRUE counted-vmcnt pipeline. A loads via inline asm (compiler
// waitcnt pass cannot see them -> our vmcnt(N) is the only wait); B DMA-staged
// double-buffered in LDS. Raw barriers; step-s+1 operands stay in flight
// across the whole MFMA phase of step s.
// Tile 128 x (32*NJ), BK=32, 4 waves 2x2, wave 64 x (16*NJ) = 4xNJ MFMA tiles.
// TERMS=3: ah*bh + ah*bl + al*bh.  TERMS=2: ah*bh + ah*bl.
template<int TERMS, int NJ>
__device__ __forceinline__ void gemm_core(
    const unsigned short* __restrict__ Ah, const unsigned short* __restrict__ Al,
    const unsigned short* __restrict__ Bh, const unsigned short* __restrict__ Bl,
    int ldkB, int kpanA, int kbeg, int kend, int m0, int n0,
    unsigned short* Bs_h, unsigned short* Bs_l,   // each [2][32*NJ*32]
    f32x4 (&acc)[4][NJ])
{
    const int tid  = threadIdx.x;
    const int lane = tid & 63;
    const int wv   = tid >> 6;
    const int wm   = (wv >> 1) * 64;
    const int wn   = (wv & 1) * (16 * NJ);
    const int lr   = lane & 15;
    const int quad = lane >> 4;
    const int BUFE = 1024 * NJ;            // elems per h/l LDS buffer
    // vm ops issued per wave per step: A-prefetch (TERMS==3 ? 8 : 4) + NJ DMA
    constexpr int VM_N = (TERMS == 3 ? 8 : 4) + NJ;

    // --- B staging: waves {0,1} -> Bs_h, waves {2,3} -> Bs_l; NJ insts/wave ---
    const unsigned short* gsrc = (wv < 2) ? Bh : Bl;
    unsigned short* ldst = (wv < 2) ? Bs_h : Bs_l;
    const int tt0  = (wv & 1) * NJ;
    const int lrow = lane >> 2;
    const int gseg = ((lane & 3) - ((lane >> 3) & 3)) & 3;  // store-side swizzle
    const size_t bstep = (size_t)16 * (size_t)ldkB;         // 16 B-rows
    const unsigned short* gp0 =
        gsrc + (size_t)(n0 + tt0 * 16 + lrow) * ldkB + kbeg + gseg * 8;

    // --- A frag base: swizzled layout -> contiguous lane*16B loads ---
    const int pk0 = kbeg >> 5;
    const size_t astr  = (size_t)kpanA * 512;               // per 16-row panel
    const size_t abase = (size_t)((m0 + wm) >> 4) * astr + (size_t)pk0 * 512
                       + (size_t)lane * 8;
    const unsigned short* ap0 = Ah + abase;
    const unsigned short* al0 = (TERMS == 3) ? (Al + abase) : nullptr;

    const int rdseg = (quad + (lr >> 1)) & 3;               // LDS read-side swizzle

    // prologue: DMA first B slab into buf 0; asm-load A(0) into set c
#pragma unroll
    for (int u = 0; u < NJ; ++u)
        gld16(gp0 + (size_t)u * bstep, ldst + (tt0 + u) * 512);

    bf16x8 cah[4], cal[4], nah[4], nal[4];
#pragma unroll
    for (int i = 0; i < 4; ++i) {
        cah[i] = gload16(ap0 + (size_t)i * astr);
        if (TERMS == 3) cal[i] = gload16(al0 + (size_t)i * astr);
    }

    const int nsteps = (kend - kbeg) >> 5;   // always even here (32 or 16)
    int buf = 0;

    // One K-step (true counted-vmcnt):
    //   BAR1: all waves done reading buf^1 (step s-1 ds_reads retired before
    //         their MFMAs, which precede the barrier in program order).
    //   issue A(s+1) asm loads + DMA(s+1) into buf^1.
    //   vmcnt(VM_N): retires A(s)+DMA(s) exactly; s+1 ops stay in flight.
    //   BAR2: every wave passed its vmcnt -> all DMA(s) LDS writes visible.
    //   sched_barrier(0): nothing (esp. MFMA reading A regs) hoists above.
    //   ds_read B(s) from buf (compiler-managed lgkmcnt), MFMA on A(s) regs.
#define GSTEP(S, CH, CL, NH, NL)                                              \
    {                                                                         \
        RAW_BARRIER();                                                        \
        if ((S) + 1 < nsteps) {                                               \
            const size_t aoff = (size_t)((S) + 1) * 512;                      \
            _Pragma("unroll")                                                 \
            for (int i = 0; i < 4; ++i) {                                     \
                NH[i] = gload16(ap0 + (size_t)i * astr + aoff);               \
                if (TERMS == 3)                                               \
                    NL[i] = gload16(al0 + (size_t)i * astr + aoff);           \
            }                                                                 \
            const size_t goff = (size_t)((S) + 1) * 32;                       \
            unsigned short* dst = ldst + (buf ^ 1) * BUFE;                    \
            _Pragma("unroll")                                                 \
            for (int u = 0; u < NJ; ++u)                                      \
                gld16(gp0 + (size_t)u * bstep + goff, dst + (tt0 + u) * 512); \
            vmwait<VM_N>();                                                   \
        } else {                                                              \
            vmwait<0>();                                                      \
        }                                                                     \
        RAW_BARRIER();                                                        \
        __builtin_amdgcn_sched_barrier(0);                                    \
        const int rbase = buf * BUFE + (wn + lr) * 32 + rdseg * 8;            \
        _Pragma("unroll")                                                     \
        for (int j = 0; j < NJ; ++j) {                                        \
            const bf16x8 bh = *(const bf16x8*)(Bs_h + rbase + j * 512);       \
            const bf16x8 bl = *(const bf16x8*)(Bs_l + rbase + j * 512);       \
            _Pragma("unroll")                                                 \
            for (int i = 0; i < 4; ++i) {                                     \
                acc[i][j] = __builtin_amdgcn_mfma_f32_16x16x32_bf16(          \
                    CH[i], bh, acc[i][j], 0, 0, 0);                           \
                acc[i][j] = __builtin_amdgcn_mfma_f32_16x16x32_bf16(          \
                    CH[i], bl, acc[i][j], 0, 0, 0);                           \
                if (TERMS == 3)                                               \
                    acc[i][j] = __builtin_amdgcn_mfma_f32_16x16x32_bf16(      \
                        CL[i], bh, acc[i][j], 0, 0, 0);                       \
            }                                                                 \
        }                                                                     \
        buf ^= 1;                                                             \
    }

    for (int s = 0; s < nsteps; s += 2) {
        GSTEP(s,     cah, cal, nah, nal);
        GSTEP(s + 1, nah, nal, cah, cal);
    }
#undef GSTEP
    // LDS is dead after the loop; epilogue (global writes) needs no barrier.
}

#define GEMM_PROLOGUE(NJ_)                                              \
    __shared__ __align__(16) unsigned short Bs_h[2 * 1024 * (NJ_)];     \
    __shared__ __align__(16) unsigned short Bs_l[2 * 1024 * (NJ_)];     \
    f32x4 acc[4][(NJ_)];                                                \
    _Pragma("unroll") for (int i = 0; i < 4; ++i)                       \
    _Pragma("unroll") for (int j = 0; j < (NJ_); ++j)                   \
    _Pragma("unroll") for (int r = 0; r < 4; ++r) acc[i][j][r] = 0.f;   \
    const int lane = threadIdx.x & 63;                                  \
    const int wv   = threadIdx.x >> 6;                                  \
    const int wm   = (wv >> 1) * 64;                                    \
    const int wn   = (wv & 1) * (16 * (NJ_));                           \
    const int lr   = lane & 15;                                         \
    const int quad = lane >> 4;                                         \
    (void)lane; (void)wv; (void)wm; (void)wn;

// ---------------------------------------------------------------------------
// ALL FOUR convs, one launch. 128x128 tiles (NJ=4). 640 blocks:
// mt (0..19) x nx (0..31); mt partitions [Wq(4) | Wk1(4) | Wk2(4) | Wv(8)].
// XCD-swizzled (640 % 8 == 0, bijective): XCD d owns wg in [80d, 80d+80).
// __launch_bounds__(256,3): 3 blocks/CU resident (32 KB LDS each; reg budget
// ~170 >= ~148 footprint so NO spills) -> 12 waves/CU of TLP.
__global__ __launch_bounds__(256, 3) void conv_all_k(
    const unsigned short* __restrict__ Wqh, const unsigned short* __restrict__ Wql,
    const unsigned short* __restrict__ Wk1h, const unsigned short* __restrict__ Wk1l,
    const unsigned short* __restrict__ Wk2h, const unsigned short* __restrict__ Wk2l,
    const unsigned short* __restrict__ Wvh, const unsigned short* __restrict__ Wvl,
    const unsigned short* __restrict__ xmTh, const unsigned short* __restrict__ xmTl,
    const unsigned short* __restrict__ xfTh, const unsigned short* __restrict__ xfTl,
    const unsigned short* __restrict__ xlTh, const unsigned short* __restrict__ xlTl,
    const float* __restrict__ bq, const float* __restrict__ bk1,
    const float* __restrict__ bk2, const float* __restrict__ bv,
    unsigned short* __restrict__ Qh, unsigned short* __restrict__ Ql,
    unsigned short* __restrict__ Kfh, unsigned short* __restrict__ Kfl,
    unsigned short* __restrict__ Klh, unsigned short* __restrict__ Kll,
    float* __restrict__ V)
{
    GEMM_PROLOGUE(4);
    // XCD-aware bijective swizzle: XCD d owns wg in [80d, 80d+80)
    const int lid = blockIdx.y * 32 + blockIdx.x;        // 0..639
    const int wg  = (lid & 7) * 80 + (lid >> 3);
    const int mt  = wg >> 5;                             // 0..19
    const int n0  = (wg & 31) * 128;

    const unsigned short *Ah, *Al, *Bh, *Bl;
    const float* bias;
    unsigned short *Ch = nullptr, *Cl = nullptr;
    float* Cv = nullptr;
    int mloc, mode;
    if (mt < 4) {
        Ah = Wqh;  Al = Wql;  Bh = xmTh; Bl = xmTl; bias = bq;
        Ch = Qh;   Cl = Ql;   mloc = mt * 128;        mode = 0;
    } else if (mt < 8) {
        Ah = Wk1h; Al = Wk1l; Bh = xfTh; Bl = xfTl; bias = bk1;
        Ch = Kfh;  Cl = Kfl;  mloc = (mt - 4) * 128;  mode = 1;
    } else if (mt < 12) {
        Ah = Wk2h; Al = Wk2l; Bh = xlTh; Bl = xlTl; bias = bk2;
        Ch = Klh;  Cl = Kll;  mloc = (mt - 8) * 128;  mode = 1;
    } else {
        Ah = Wvh;  Al = Wvl;  Bh = xmTh; Bl = xmTl; bias = bv;
        Cv = V;    mloc = (mt - 12) * 128;            mode = 2;
    }

    gemm_core<3, 4>(Ah, Al, Bh, Bl, 1024, 32, 0, 1024, mloc, n0, Bs_h, Bs_l, acc);

#pragma unroll
    for (int i = 0; i < 4; ++i) {
        const int mb = mloc + wm + i * 16 + quad * 4;
#pragma unroll
        for (int j = 0; j < 4; ++j) {
            const int nn = n0 + wn + j * 16 + lr;
#pragma unroll
            for (int r = 0; r < 4; ++r) {
                const float v = acc[i][j][r] + bias[mb + r];
                if (mode == 2) {
                    Cv[(size_t)(mb + r) * 4096 + nn] = v;
                } else if (mode == 0) {
                    unsigned short h, l;
                    split2(v, h, l);
                    const size_t idx = (size_t)(mb + r) * 4096 + nn;
                    Ch[idx] = h;
                    Cl[idx] = l;
                } else {
                    // swizzled store for logits-A view [1024][2048]
                    const int m2 = ((mb + r) << 1) | (nn >> 11);
                    const int k2 = nn & 2047;
                    const size_t o = swz(m2, k2, 64);
                    unsigned short h, l;
                    split2(v, h, l);
                    Ch[o] = h;
                    Cl[o] = l;
                }
            }
        }
    }
}

// ---------------------------------------------------------------------------
// Fused logits, split-K, 128x128 tiles (NJ=4). 512 blocks:
// z = which(f/l)*4 + kslice(0..3), m-tile(0..7), n-tile(0..7).
// XCD-swizzled so each XCD owns one full z-slice (A 2MB + Q 2MB fit 4MB L2).
__global__ __launch_bounds__(256, 3) void logits_fused_k(
    const unsigned short* __restrict__ Kfh, const unsigned short* __restrict__ Kfl,
    const unsigned short* __restrict__ Klh, const unsigned short* __restrict__ Kll,
    const unsigned short* __restrict__ Qh, const unsigned short* __restrict__ Ql,
    float* __restrict__ Sfp, float* __restrict__ Slp)
{
    GEMM_PROLOGUE(4);
    const int lid = (blockIdx.z * 8 + blockIdx.y) * 8 + blockIdx.x;  // 0..511
    const int wg  = (lid & 7) * 64 + (lid >> 3);
    const int bx  = wg & 7;
    const int by  = (wg >> 3) & 7;
    const int bz  = wg >> 6;

    const int which = bz >> 2;
    const int slice = bz & 3;
    const unsigned short* Ah = which ? Klh : Kfh;
    const unsigned short* Al = which ? Kll : Kfl;
    float* out = (which ? Slp : Sfp) + (size_t)slice * 1024 * 1024;
    const int m0 = by * 128;
    const int n0 = bx * 128;

    gemm_core<3, 4>(Ah, Al, Qh, Ql, 2048, 64, slice * 512, slice * 512 + 512,
                    m0, n0, Bs_h, Bs_l, acc);

#pragma unroll
    for (int i = 0; i < 4; ++i) {
        const int mb = m0 + wm + i * 16 + quad * 4;
#pragma unroll
        for (int j = 0; j < 4; ++j) {
            const int nn = n0 + wn + j * 16 + lr;
#pragma unroll
            for (int r = 0; r < 4; ++r)
                out[(size_t)(mb + r) * 1024 + nn] = acc[i][j][r];
        }
    }
}

// ---------------------------------------------------------------------------
// Final: out = gamma*(A (x) VT) + 0.5*(xf+xl). A = Am swizzled (kpan=32),
// B = VT row-major ldk=1024. NJ=4, 256 blocks. 2-term.
__global__ __launch_bounds__(256, 3) void gemm_final_k(
    const unsigned short* __restrict__ Amh,
    const unsigned short* __restrict__ VTh, const unsigned short* __restrict__ VTl,
    float* __restrict__ out,
    const float* __restrict__ xf, const float* __restrict__ xl,
    const float* __restrict__ gamma)
{
    GEMM_PROLOGUE(4);
    const int m0 = blockIdx.y * 128;
    const int n0 = blockIdx.x * 128;

    gemm_core<2, 4>(Amh, nullptr, VTh, VTl, 1024, 32, 0, 1024, m0, n0,
                    Bs_h, Bs_l, acc);

    const float g = gamma[0];
#pragma unroll
    for (int i = 0; i < 4; ++i) {
        const int mb = m0 + wm + i * 16 + quad * 4;
#pragma unroll
        for (int j = 0; j < 4; ++j) {
            const int nn = n0 + wn + j * 16 + lr;
#pragma unroll
            for (int r = 0; r < 4; ++r) {
                const size_t idx = (size_t)(mb + r) * 4096 + nn;
                out[idx] = g * acc[i][j][r] + 0.5f * (xf[idx] + xl[idx]);
            }
        }
    }
}

// ---------------------------------------------------------------------------
// Row softmax over 4-slice partial sums: A = sm(sum Sfp) + sm(sum Slp),
// bf16 hi only (final GEMM is 2-term), stored SWIZZLED (kpan=32).
__global__ __launch_bounds__(256) void softmax_add4_k(
    const float* __restrict__ Sfp, const float* __restrict__ Slp,
    unsigned short* __restrict__ Ah)
{
    const int row = blockIdx.x;
    const int tid = threadIdx.x;
    __shared__ float red[8];
    const size_t base = (size_t)row * 1024 + tid * 4;
    const size_t SL = (size_t)1024 * 1024;

    float4 vf = *(const float4*)(Sfp + base);
    float4 vl = *(const float4*)(Slp + base);
#pragma unroll
    for (int s = 1; s < 4; ++s) {
        const float4 a = *(const float4*)(Sfp + s * SL + base);
        const float4 b = *(const float4*)(Slp + s * SL + base);
        vf.x += a.x; vf.y += a.y; vf.z += a.z; vf.w += a.w;
        vl.x += b.x; vl.y += b.y; vl.z += b.z; vl.w += b.w;
    }

    float mf = fmaxf(fmaxf(vf.x, vf.y), fmaxf(vf.z, vf.w));
    float ml = fmaxf(fmaxf(vl.x, vl.y), fmaxf(vl.z, vl.w));
#pragma unroll
    for (int off = 32; off; off >>= 1) {
        mf = fmaxf(mf, __shfl_down(mf, off, 64));
        ml = fmaxf(ml, __shfl_down(ml, off, 64));
    }
    const int wave = tid >> 6;
    if ((tid & 63) == 0) { red[wave] = mf; red[4 + wave] = ml; }
    __syncthreads();
    mf = fmaxf(fmaxf(red[0], red[1]), fmaxf(red[2], red[3]));
    ml = fmaxf(fmaxf(red[4], red[5]), fmaxf(red[6], red[7]));
    __syncthreads();

    const float4 ef = make_float4(expf(vf.x - mf), expf(vf.y - mf),
                                  expf(vf.z - mf), expf(vf.w - mf));
    const float4 el = make_float4(expf(vl.x - ml), expf(vl.y - ml),
                                  expf(vl.z - ml), expf(vl.w - ml));
    float sf = ef.x + ef.y + ef.z + ef.w;
    float sl = el.x + el.y + el.z + el.w;
#pragma unroll
    for (int off = 32; off; off >>= 1) {
        sf += __shfl_down(sf, off, 64);
        sl += __shfl_down(sl, off, 64);
    }
    if ((tid & 63) == 0) { red[wave] = sf; red[4 + wave] = sl; }
    __syncthreads();
    sf = red[0] + red[1] + red[2] + red[3];
    sl = red[4] + red[5] + red[6] + red[7];

    const float rf = 1.f / sf, rl = 1.f / sl;
    ushort4 h;
    h.x = f2bf(ef.x * rf + el.x * rl);
    h.y = f2bf(ef.y * rf + el.y * rl);
    h.z = f2bf(ef.z * rf + el.z * rl);
    h.w = f2bf(ef.w * rf + el.w * rl);
    const size_t o = swz(row, tid * 4, 32);   // 4 elems contiguous ((4t)&7 in {0,4})
    *(ushort4*)(Ah + o) = h;
}

__global__ void noop_k(float* p) { if (threadIdx.x == 1024) p[0] = 0.f; }

// ===========================================================================
extern "C" void kernel_launch(void* const* d_in, const int* in_sizes, int n_in,
                              void* d_out, int out_size, void* d_ws, size_t ws_size,
                              hipStream_t stream) {
    (void)in_sizes; (void)n_in; (void)out_size;
    const float* xf  = (const float*)d_in[0];
    const float* xm  = (const float*)d_in[1];
    const float* xl  = (const float*)d_in[2];
    const float* Wq  = (const float*)d_in[3];
    const float* bq  = (const float*)d_in[4];
    const float* Wk1 = (const float*)d_in[5];
    const float* bk1 = (const float*)d_in[6];
    const float* Wk2 = (const float*)d_in[7];
    const float* bk2 = (const float*)d_in[8];
    const float* Wv  = (const float*)d_in[9];
    const float* bv  = (const float*)d_in[10];
    const float* gamma = (const float*)d_in[11];
    float* out = (float*)d_out;

    const size_t MB = 1024 * 1024;
    if (ws_size < 98 * MB) {
        noop_k<<<dim3(1), dim3(64), 0, stream>>>((float*)d_ws);
        return;
    }

    // ---- workspace layout (byte offsets, 98 MB total) ----
    char* p = (char*)d_ws;
    unsigned short* xmT_h = (unsigned short*)(p + 0 * MB);    // [4096][1024] bf16, row-major
    unsigned short* xmT_l = (unsigned short*)(p + 8 * MB);
    unsigned short* xfT_h = (unsigned short*)(p + 16 * MB);
    unsigned short* xfT_l = (unsigned short*)(p + 24 * MB);
    unsigned short* xlT_h = (unsigned short*)(p + 32 * MB);
    unsigned short* xlT_l = (unsigned short*)(p + 40 * MB);
    unsigned short* Wq_h  = (unsigned short*)(p + 48 * MB);   // swizzled
    unsigned short* Wq_l  = (unsigned short*)(p + 49 * MB);
    unsigned short* Wk1_h = (unsigned short*)(p + 50 * MB);
    unsigned short* Wk1_l = (unsigned short*)(p + 51 * MB);
    unsigned short* Wk2_h = (unsigned short*)(p + 52 * MB);
    unsigned short* Wk2_l = (unsigned short*)(p + 53 * MB);
    unsigned short* Wv_h  = (unsigned short*)(p + 54 * MB);
    unsigned short* Wv_l  = (unsigned short*)(p + 56 * MB);
    unsigned short* Q_h   = (unsigned short*)(p + 58 * MB);   // row-major [1024][2048]
    unsigned short* Q_l   = (unsigned short*)(p + 62 * MB);
    unsigned short* Kf_h  = (unsigned short*)(p + 66 * MB);   // swizzled [1024][2048]
    unsigned short* Kf_l  = (unsigned short*)(p + 70 * MB);
    unsigned short* Kl_h  = (unsigned short*)(p + 74 * MB);
    unsigned short* Kl_l  = (unsigned short*)(p + 78 * MB);
    float*          V     = (float*)(p + 82 * MB);            // [1024][4096] f32 (+bias)
    // lifetime-based reuse (launch order: convs -> logits -> V transpose ->
    // softmax -> final):
    float*          Sfp  = (float*)(p + 16 * MB);  // [4][1024][1024] over xfT (dead after convs)
    float*          Slp  = (float*)(p + 32 * MB);  // over xlT
    unsigned short* VT_h = xmT_h;                  // over xmT (dead after convs)
    unsigned short* VT_l = xmT_l;
    unsigned short* Am_h = (unsigned short*)(p + 74 * MB);  // swizzled, over Kl (dead after logits)

    const dim3 blk(256);
    // prep (2 launches): transpose+split the 3 inputs; split the 4 weights
    transpose3_k<<<dim3(128, 32, 3), blk, 0, stream>>>(
        xm, xf, xl, xmT_h, xmT_l, xfT_h, xfT_l, xlT_h, xlT_l);
    weights_split_k<<<dim3(2560), blk, 0, stream>>>(
        Wq, Wk1, Wk2, Wv, Wq_h, Wq_l, Wk1_h, Wk1_l, Wk2_h, Wk2_l, Wv_h, Wv_l);
    // ALL convs, one launch (640 blocks, 128x128 tiles, XCD-swizzled)
    conv_all_k<<<dim3(32, 20), blk, 0, stream>>>(
        Wq_h, Wq_l, Wk1_h, Wk1_l, Wk2_h, Wk2_l, Wv_h, Wv_l,
        xmT_h, xmT_l, xfT_h, xfT_l, xlT_h, xlT_l,
        bq, bk1, bk2, bv,
        Q_h, Q_l, Kf_h, Kf_l, Kl_h, Kl_l, V);
    // logits fused + split-K=4 (512 blocks, 128x128 tiles, XCD z-sliced)
    logits_fused_k<<<dim3(8, 8, 8), blk, 0, stream>>>(
        Kf_h, Kf_l, Kl_h, Kl_l, Q_h, Q_l, Sfp, Slp);
    // VT = transpose+split(V) over dead xmT region
    transpose1_k<<<dim3(128, 32), blk, 0, stream>>>(V, VT_h, VT_l);
    // A = softmax(sum Sfp) + softmax(sum Slp), swizzled bf16-hi over dead Kl
    softmax_add4_k<<<dim3(1024), blk, 0, stream>>>(Sfp, Slp, Am_h);
    // out = gamma*(A (x) VT) + (xf+xl)/2   (256 blocks)
    gemm_final_k<<<dim3(32, 8), blk, 0, stream>>>(
        Am_h, VT_h, VT_l, out, xf, xl, gamma);
}

// Round 9
// 278.262 us; speedup vs baseline: 1.0112x; 1.0112x over previous
//
#include <hip/hip_runtime.h>
#include <math.h>

// ===========================================================================
// CoAtten2: C=1024, H=W=64, HW=4096. Split-bf16 MFMA pipeline (3-term:
// ah*bh + ah*bl + al*bh; final GEMM 2-term with A=probs).
//
// R16 changes vs R15 (R15==R13: launch_bounds(256,3) was a no-op -> occupancy
// is REGISTER-capped at 2 blocks/CU (VGPR_Count=84 excludes acc/unified regs;
// true footprint ~200). Remaining stall: ~1700cy/step where both resident
// waves wait together; FETCH 167MB vs 58MB unique -> 26% L2 miss -> L3/HBM
// latency > the single step-slot of prefetch cover):
//   - B-PREFETCH DEPTH 2: LDS B buffers triple-buffered (3x16KB h + 3x16KB l
//     = 48KB/block; 2 blocks = 96KB <= 160KB). DMA for step s+2 issued at
//     step s -> two full step-slots (~5000cy) of latency cover on B.
//     A stays 1-ahead (a 3rd A reg set would raise the footprint that
//     already caps occupancy).
//   - vmcnt ladder (FIFO-exact): prologue issues D(0),A(0),D(1); step s
//     issues A(s+1),D(s+2); steady-state wait keeps {A(s+1),D(s+1),D(s+2)}
//     = 16 ops (3-term) / 12 (2-term); tail keeps 12/8; last step 0.
//   - Buffer reuse safety: step s writes buf[(s+2)%3], last read at step
//     s-1; BAR1 at step s is after all waves' step s-1 reads. Math and
//     accumulation order identical: absmax must stay exactly 0.015625.
// ===========================================================================

typedef __attribute__((ext_vector_type(8))) short    bf16x8;   // MFMA A/B frag
typedef __attribute__((ext_vector_type(4))) float    f32x4;    // MFMA C/D frag

__device__ __forceinline__ unsigned short f2bf(float x) {
    unsigned u = __float_as_uint(x);
    u += 0x7FFFu + ((u >> 16) & 1u);    // round-to-nearest-even
    return (unsigned short)(u >> 16);
}
__device__ __forceinline__ float bf2f(unsigned short h) {
    return __uint_as_float(((unsigned)h) << 16);
}
__device__ __forceinline__ void split2(float x, unsigned short& h, unsigned short& l) {
    h = f2bf(x);
    l = f2bf(x - bf2f(h));
}

// Frag-major (swizzled) offset for an A-operand matrix [M][K], kpan = K/32.
__device__ __forceinline__ size_t swz(int m, int k, int kpan) {
    return ((size_t)((m >> 4) * kpan + (k >> 5))) * 512
         + (size_t)((((k >> 3) & 3) * 16 + (m & 15)) * 8 + (k & 7));
}

// Async global->LDS DMA, 16B per lane. LDS dest = wave-uniform base + lane*16.
__device__ __forceinline__ void gld16(const unsigned short* g, unsigned short* l) {
    __builtin_amdgcn_global_load_lds(
        (const __attribute__((address_space(1))) unsigned int*)g,
        (__attribute__((address_space(3))) unsigned int*)l,
        16, 0, 0);
}

// 16B global load via inline asm: NOT tracked by the compiler's waitcnt pass.
// Caller is responsible for s_waitcnt vmcnt(N) before reading the result.
__device__ __forceinline__ bf16x8 gload16(const unsigned short* p) {
    bf16x8 r;
    asm volatile("global_load_dwordx4 %0, %1, off"
                 : "=v"(r) : "v"(p) : "memory");
    return r;
}

// Raw workgroup barrier WITHOUT the __syncthreads vmcnt(0) drain.
#define RAW_BARRIER() asm volatile("s_barrier" ::: "memory")

// Exact counted vmem wait: allow N newest ops to stay in flight.
template<int N>
__device__ __forceinline__ void vmwait() {
    asm volatile("s_waitcnt vmcnt(%0)" :: "i"(N) : "memory");
}

// ---------------------------------------------------------------------------
// All-weights split -> SWIZZLED h/l (weights are GEMM-A operands, kpan=32).
__global__ __launch_bounds__(256) void weights_split_k(
    const float* __restrict__ Wq, const float* __restrict__ Wk1,
    const float* __restrict__ Wk2, const float* __restrict__ Wv,
    unsigned short* __restrict__ Wqh, unsigned short* __restrict__ Wql,
    unsigned short* __restrict__ Wk1h, unsigned short* __restrict__ Wk1l,
    unsigned short* __restrict__ Wk2h, unsigned short* __restrict__ Wk2l,
    unsigned short* __restrict__ Wvh, unsigned short* __restrict__ Wvl)
{
    const int gi = blockIdx.x;
    const float* src; unsigned short *H, *L; int base;
    if (gi < 512)       { src = Wq;  H = Wqh;  L = Wql;  base = gi; }
    else if (gi < 1024) { src = Wk1; H = Wk1h; L = Wk1l; base = gi - 512; }
    else if (gi < 1536) { src = Wk2; H = Wk2h; L = Wk2l; base = gi - 1024; }
    else                { src = Wv;  H = Wvh;  L = Wvl;  base = gi - 1536; }
    const size_t i = (size_t)base * 1024 + threadIdx.x * 4;
    const int m = (int)(i >> 10);
    const int k = (int)(i & 1023);
    const float4 v = *(const float4*)(src + i);
    ushort4 h, l;
    split2(v.x, h.x, l.x); split2(v.y, h.y, l.y);
    split2(v.z, h.z, l.z); split2(v.w, h.w, l.w);
    const size_t o = swz(m, k, 32);      // k&7 in {0,4}: 4 elems contiguous
    *(ushort4*)(H + o) = h;
    *(ushort4*)(L + o) = l;
}

// ---------------------------------------------------------------------------
// Transpose + split for the 3 inputs in one launch (z selects which).
__global__ __launch_bounds__(256) void transpose3_k(
    const float* __restrict__ x0, const float* __restrict__ x1,
    const float* __restrict__ x2,
    unsigned short* __restrict__ t0h, unsigned short* __restrict__ t0l,
    unsigned short* __restrict__ t1h, unsigned short* __restrict__ t1l,
    unsigned short* __restrict__ t2h, unsigned short* __restrict__ t2l)
{
    const float* X; unsigned short *Th, *Tl;
    if (blockIdx.z == 0)      { X = x0; Th = t0h; Tl = t0l; }
    else if (blockIdx.z == 1) { X = x1; Th = t1h; Tl = t1l; }
    else                      { X = x2; Th = t2h; Tl = t2l; }

    __shared__ float t[32 * 33];
    const int tid = threadIdx.x;
    const int c0 = blockIdx.y * 32;
    const int p0 = blockIdx.x * 32;

    const int cl = tid >> 3;
    const int p4 = (tid & 7) * 4;
    const float4 v = *(const float4*)(X + (size_t)(c0 + cl) * 4096 + p0 + p4);
    t[(p4 + 0) * 33 + cl] = v.x;
    t[(p4 + 1) * 33 + cl] = v.y;
    t[(p4 + 2) * 33 + cl] = v.z;
    t[(p4 + 3) * 33 + cl] = v.w;
    __syncthreads();

    const int pl = tid >> 3;
    const int c4 = (tid & 7) * 4;
    ushort4 h, l;
    split2(t[pl * 33 + c4 + 0], h.x, l.x);
    split2(t[pl * 33 + c4 + 1], h.y, l.y);
    split2(t[pl * 33 + c4 + 2], h.z, l.z);
    split2(t[pl * 33 + c4 + 3], h.w, l.w);
    const size_t o = (size_t)(p0 + pl) * 1024 + c0 + c4;
    *(ushort4*)(Th + o) = h;
    *(ushort4*)(Tl + o) = l;
}

// Single-matrix transpose+split, row-major output (VT = B of final GEMM).
__global__ __launch_bounds__(256) void transpose1_k(
    const float* __restrict__ X,
    unsigned short* __restrict__ Th, unsigned short* __restrict__ Tl)
{
    __shared__ float t[32 * 33];
    const int tid = threadIdx.x;
    const int c0 = blockIdx.y * 32;
    const int p0 = blockIdx.x * 32;

    const int cl = tid >> 3;
    const int p4 = (tid & 7) * 4;
    const float4 v = *(const float4*)(X + (size_t)(c0 + cl) * 4096 + p0 + p4);
    t[(p4 + 0) * 33 + cl] = v.x;
    t[(p4 + 1) * 33 + cl] = v.y;
    t[(p4 + 2) * 33 + cl] = v.z;
    t[(p4 + 3) * 33 + cl] = v.w;
    __syncthreads();

    const int pl = tid >> 3;
    const int c4 = (tid & 7) * 4;
    ushort4 h, l;
    split2(t[pl * 33 + c4 + 0], h.x, l.x);
    split2(t[pl * 33 + c4 + 1], h.y, l.y);
    split2(t[pl * 33 + c4 + 2], h.z, l.z);
    split2(t[pl * 33 + c4 + 3], h.w, l.w);
    const size_t o = (size_t)(p0 + pl) * 1024 + c0 + c4;
    *(ushort4*)(Th + o) = h;
    *(ushort4*)(Tl + o) = l;
}

// ---------------------------------------------------------------------------
// GEMM core v8: counted-vmcnt pipeline, B prefetch depth 2 (triple-buffered
// LDS), A register prefetch depth 1. A loads via inline asm (invisible to the
// compiler's waitcnt pass -> our vmcnt(N) is the only wait).
// Tile 128 x (32*NJ), BK=32, 4 waves 2x2, wave 64 x (16*NJ) = 4xNJ MFMA tiles.
// TERMS=3: ah*bh + ah*bl + al*bh.  TERMS=2: ah*bh + ah*bl.
template<int TERMS, int NJ>
__device__ __forceinline__ void gemm_core(
    const unsigned short* __restrict__ Ah, const unsigned short* __restrict__ Al,
    const unsigned short* __restrict__ Bh, const unsigned short* __restrict__ Bl,
    int ldkB, int kpanA, int kbeg, int kend, int m0, int n0,
    unsigned short* Bs_h, unsigned short* Bs_l,   // each [3][32*NJ*32]
    f32x4 (&acc)[4][NJ])
{
    const int tid  = threadIdx.x;
    const int lane = tid & 63;
    const int wv   = tid >> 6;
    const int wm   = (wv >> 1) * 64;
    const int wn   = (wv & 1) * (16 * NJ);
    const int lr   = lane & 15;
    const int quad = lane >> 4;
    const int BUFE = 1024 * NJ;            // elems per h/l LDS buffer
    constexpr int AOPS = (TERMS == 3 ? 8 : 4);
    // steady-state in-flight kept: A(s+1) + D(s+1) + D(s+2)
    constexpr int VM_FULL = AOPS + NJ + NJ;
    // tail (s+2==nsteps): keep A(s+1) + D(s+1)
    constexpr int VM_MID  = AOPS + NJ;

    // --- B staging: waves {0,1} -> Bs_h, waves {2,3} -> Bs_l; NJ insts/wave ---
    const unsigned short* gsrc = (wv < 2) ? Bh : Bl;
    unsigned short* ldst = (wv < 2) ? Bs_h : Bs_l;
    const int tt0  = (wv & 1) * NJ;
    const int lrow = lane >> 2;
    const int gseg = ((lane & 3) - ((lane >> 3) & 3)) & 3;  // store-side swizzle
    const size_t bstep = (size_t)16 * (size_t)ldkB;         // 16 B-rows
    const unsigned short* gp0 =
        gsrc + (size_t)(n0 + tt0 * 16 + lrow) * ldkB + kbeg + gseg * 8;

    // --- A frag base: swizzled layout -> contiguous lane*16B loads ---
    const int pk0 = kbeg >> 5;
    const size_t astr  = (size_t)kpanA * 512;               // per 16-row panel
    const size_t abase = (size_t)((m0 + wm) >> 4) * astr + (size_t)pk0 * 512
                       + (size_t)lane * 8;
    const unsigned short* ap0 = Ah + abase;
    const unsigned short* al0 = (TERMS == 3) ? (Al + abase) : nullptr;

    const int rdseg = (quad + (lr >> 1)) & 3;               // LDS read-side swizzle

    const int nsteps = (kend - kbeg) >> 5;   // conv/final 32, logits 16 (even)

    // prologue (FIFO order matters for the vmcnt ladder):
    //   DMA(0)->buf0, A(0)->regs, DMA(1)->buf1
#pragma unroll
    for (int u = 0; u < NJ; ++u)
        gld16(gp0 + (size_t)u * bstep, ldst + 0 * BUFE + (tt0 + u) * 512);

    bf16x8 cah[4], cal[4], nah[4], nal[4];
#pragma unroll
    for (int i = 0; i < 4; ++i) {
        cah[i] = gload16(ap0 + (size_t)i * astr);
        if (TERMS == 3) cal[i] = gload16(al0 + (size_t)i * astr);
    }
#pragma unroll
    for (int u = 0; u < NJ; ++u)
        gld16(gp0 + (size_t)u * bstep + 32, ldst + 1 * BUFE + (tt0 + u) * 512);

    int br = 0;            // read buffer for current step  (s % 3)
    int bw = 2;            // write buffer for step s+2     ((s+2) % 3)

    // One K-step:
    //   BAR1: all waves done reading buf bw (last read at step s-1).
    //   issue A(s+1) asm loads; issue DMA(s+2) into buf bw.
    //   vmcnt(N): retires A(s)+D(s); keeps {A(s+1), D(s+1), D(s+2)}.
    //   BAR2 + sched_barrier: all waves' D(s) LDS writes visible; no hoist.
    //   ds_read B(s) from buf br (compiler lgkmcnt), MFMA on A(s) regs.
#define GSTEP(S, CH, CL, NH, NL)                                              \
    {                                                                         \
        RAW_BARRIER();                                                        \
        const bool hasA = (S) + 1 < nsteps;                                   \
        const bool hasD = (S) + 2 < nsteps;                                   \
        if (hasA) {                                                           \
            const size_t aoff = (size_t)((S) + 1) * 512;                      \
            _Pragma("unroll")                                                 \
            for (int i = 0; i < 4; ++i) {                                     \
                NH[i] = gload16(ap0 + (size_t)i * astr + aoff);               \
                if (TERMS == 3)                                               \
                    NL[i] = gload16(al0 + (size_t)i * astr + aoff);           \
            }                                                                 \
        }                                                                     \
        if (hasD) {                                                           \
            const size_t goff = (size_t)((S) + 2) * 32;                       \
            unsigned short* dst = ldst + bw * BUFE;                           \
            _Pragma("unroll")                                                 \
            for (int u = 0; u < NJ; ++u)                                      \
                gld16(gp0 + (size_t)u * bstep + goff, dst + (tt0 + u) * 512); \
            vmwait<VM_FULL>();                                                \
        } else if (hasA) {                                                    \
            vmwait<VM_MID>();                                                 \
        } else {                                                              \
            vmwait<0>();                                                      \
        }                                                                     \
        RAW_BARRIER();                                                        \
        __builtin_amdgcn_sched_barrier(0);                                    \
        const int rbase = br * BUFE + (wn + lr) * 32 + rdseg * 8;             \
        _Pragma("unroll")                                                     \
        for (int j = 0; j < NJ; ++j) {                                        \
            const bf16x8 bh = *(const bf16x8*)(Bs_h + rbase + j * 512);       \
            const bf16x8 bl = *(const bf16x8*)(Bs_l + rbase + j * 512);       \
            _Pragma("unroll")                                                 \
            for (int i = 0; i < 4; ++i) {                                     \
                acc[i][j] = __builtin_amdgcn_mfma_f32_16x16x32_bf16(          \
                    CH[i], bh, acc[i][j], 0, 0, 0);                           \
                acc[i][j] = __builtin_amdgcn_mfma_f32_16x16x32_bf16(          \
                    CH[i], bl, acc[i][j], 0, 0, 0);                           \
                if (TERMS == 3)                                               \
                    acc[i][j] = __builtin_amdgcn_mfma_f32_16x16x32_bf16(      \
                        CL[i], bh, acc[i][j], 0, 0, 0);                       \
            }                                                                 \
        }                                                                     \
        br = (br == 2) ? 0 : br + 1;                                          \
        bw = (bw == 2) ? 0 : bw + 1;                                          \
    }

    for (int s = 0; s < nsteps; s += 2) {
        GSTEP(s,     cah, cal, nah, nal);
        GSTEP(s + 1, nah, nal, cah, cal);
    }
#undef GSTEP
    // LDS is dead after the loop; epilogue (global writes) needs no barrier.
}

#define GEMM_PROLOGUE(NJ_)                                              \
    __shared__ __align__(16) unsigned short Bs_h[3 * 1024 * (NJ_)];     \
    __shared__ __align__(16) unsigned short Bs_l[3 * 1024 * (NJ_)];     \
    f32x4 acc[4][(NJ_)];                                                \
    _Pragma("unroll") for (int i = 0; i < 4; ++i)                       \
    _Pragma("unroll") for (int j = 0; j < (NJ_); ++j)                   \
    _Pragma("unroll") for (int r = 0; r < 4; ++r) acc[i][j][r] = 0.f;   \
    const int lane = threadIdx.x & 63;                                  \
    const int wv   = threadIdx.x >> 6;                                  \
    const int wm   = (wv >> 1) * 64;                                    \
    const int wn   = (wv & 1) * (16 * (NJ_));                           \
    const int lr   = lane & 15;                                         \
    const int quad = lane >> 4;                                         \
    (void)lane; (void)wv; (void)wm; (void)wn;

// ---------------------------------------------------------------------------
// ALL FOUR convs, one launch. 128x128 tiles (NJ=4). 640 blocks:
// mt (0..19) x nx (0..31); mt partitions [Wq(4) | Wk1(4) | Wk2(4) | Wv(8)].
// XCD-swizzled (640 % 8 == 0, bijective): XCD d owns wg in [80d, 80d+80).
// 48 KB LDS/block -> 2 blocks/CU resident (register-capped anyway).
__global__ __launch_bounds__(256, 2) void conv_all_k(
    const unsigned short* __restrict__ Wqh, const unsigned short* __restrict__ Wql,
    const unsigned short* __restrict__ Wk1h, const unsigned short* __restrict__ Wk1l,
    const unsigned short* __restrict__ Wk2h, const unsigned short* __restrict__ Wk2l,
    const unsigned short* __restrict__ Wvh, const unsigned short* __restrict__ Wvl,
    const unsigned short* __restrict__ xmTh, const unsigned short* __restrict__ xmTl,
    const unsigned short* __restrict__ xfTh, const unsigned short* __restrict__ xfTl,
    const unsigned short* __restrict__ xlTh, const unsigned short* __restrict__ xlTl,
    const float* __restrict__ bq, const float* __restrict__ bk1,
    const float* __restrict__ bk2, const float* __restrict__ bv,
    unsigned short* __restrict__ Qh, unsigned short* __restrict__ Ql,
    unsigned short* __restrict__ Kfh, unsigned short* __restrict__ Kfl,
    unsigned short* __restrict__ Klh, unsigned short* __restrict__ Kll,
    float* __restrict__ V)
{
    GEMM_PROLOGUE(4);
    // XCD-aware bijective swizzle: XCD d owns wg in [80d, 80d+80)
    const int lid = blockIdx.y * 32 + blockIdx.x;        // 0..639
    const int wg  = (lid & 7) * 80 + (lid >> 3);
    const int mt  = wg >> 5;                             // 0..19
    const int n0  = (wg & 31) * 128;

    const unsigned short *Ah, *Al, *Bh, *Bl;
    const float* bias;
    unsigned short *Ch = nullptr, *Cl = nullptr;
    float* Cv = nullptr;
    int mloc, mode;
    if (mt < 4) {
        Ah = Wqh;  Al = Wql;  Bh = xmTh; Bl = xmTl; bias = bq;
        Ch = Qh;   Cl = Ql;   mloc = mt * 128;        mode = 0;
    } else if (mt < 8) {
        Ah = Wk1h; Al = Wk1l; Bh = xfTh; Bl = xfTl; bias = bk1;
        Ch = Kfh;  Cl = Kfl;  mloc = (mt - 4) * 128;  mode = 1;
    } else if (mt < 12) {
        Ah = Wk2h; Al = Wk2l; Bh = xlTh; Bl = xlTl; bias = bk2;
        Ch = Klh;  Cl = Kll;  mloc = (mt - 8) * 128;  mode = 1;
    } else {
        Ah = Wvh;  Al = Wvl;  Bh = xmTh; Bl = xmTl; bias = bv;
        Cv = V;    mloc = (mt - 12) * 128;            mode = 2;
    }

    gemm_core<3, 4>(Ah, Al, Bh, Bl, 1024, 32, 0, 1024, mloc, n0, Bs_h, Bs_l, acc);

#pragma unroll
    for (int i = 0; i < 4; ++i) {
        const int mb = mloc + wm + i * 16 + quad * 4;
#pragma unroll
        for (int j = 0; j < 4; ++j) {
            const int nn = n0 + wn + j * 16 + lr;
#pragma unroll
            for (int r = 0; r < 4; ++r) {
                const float v = acc[i][j][r] + bias[mb + r];
                if (mode == 2) {
                    Cv[(size_t)(mb + r) * 4096 + nn] = v;
                } else if (mode == 0) {
                    unsigned short h, l;
                    split2(v, h, l);
                    const size_t idx = (size_t)(mb + r) * 4096 + nn;
                    Ch[idx] = h;
                    Cl[idx] = l;
                } else {
                    // swizzled store for logits-A view [1024][2048]
                    const int m2 = ((mb + r) << 1) | (nn >> 11);
                    const int k2 = nn & 2047;
                    const size_t o = swz(m2, k2, 64);
                    unsigned short h, l;
                    split2(v, h, l);
                    Ch[o] = h;
                    Cl[o] = l;
                }
            }
        }
    }
}

// ---------------------------------------------------------------------------
// Fused logits, split-K, 128x128 tiles (NJ=4). 512 blocks:
// z = which(f/l)*4 + kslice(0..3), m-tile(0..7), n-tile(0..7).
// XCD-swizzled so each XCD owns one full z-slice (A 2MB + Q 2MB fit 4MB L2).
__global__ __launch_bounds__(256, 2) void logits_fused_k(
    const unsigned short* __restrict__ Kfh, const unsigned short* __restrict__ Kfl,
    const unsigned short* __restrict__ Klh, const unsigned short* __restrict__ Kll,
    const unsigned short* __restrict__ Qh, const unsigned short* __restrict__ Ql,
    float* __restrict__ Sfp, float* __restrict__ Slp)
{
    GEMM_PROLOGUE(4);
    const int lid = (blockIdx.z * 8 + blockIdx.y) * 8 + blockIdx.x;  // 0..511
    const int wg  = (lid & 7) * 64 + (lid >> 3);
    const int bx  = wg & 7;
    const int by  = (wg >> 3) & 7;
    const int bz  = wg >> 6;

    const int which = bz >> 2;
    const int slice = bz & 3;
    const unsigned short* Ah = which ? Klh : Kfh;
    const unsigned short* Al = which ? Kll : Kfl;
    float* out = (which ? Slp : Sfp) + (size_t)slice * 1024 * 1024;
    const int m0 = by * 128;
    const int n0 = bx * 128;

    gemm_core<3, 4>(Ah, Al, Qh, Ql, 2048, 64, slice * 512, slice * 512 + 512,
                    m0, n0, Bs_h, Bs_l, acc);

#pragma unroll
    for (int i = 0; i < 4; ++i) {
        const int mb = m0 + wm + i * 16 + quad * 4;
#pragma unroll
        for (int j = 0; j < 4; ++j) {
            const int nn = n0 + wn + j * 16 + lr;
#pragma unroll
            for (int r = 0; r < 4; ++r)
                out[(size_t)(mb + r) * 1024 + nn] = acc[i][j][r];
        }
    }
}

// ---------------------------------------------------------------------------
// Final: out = gamma*(A (x) VT) + 0.5*(xf+xl). A = Am swizzled (kpan=32),
// B = VT row-major ldk=1024. NJ=4, 256 blocks. 2-term.
__global__ __launch_bounds__(256, 2) void gemm_final_k(
    const unsigned short* __restrict__ Amh,
    const unsigned short* __restrict__ VTh, const unsigned short* __restrict__ VTl,
    float* __restrict__ out,
    const float* __restrict__ xf, const float* __restrict__ xl,
    const float* __restrict__ gamma)
{
    GEMM_PROLOGUE(4);
    const int m0 = blockIdx.y * 128;
    const int n0 = blockIdx.x * 128;

    gemm_core<2, 4>(Amh, nullptr, VTh, VTl, 1024, 32, 0, 1024, m0, n0,
                    Bs_h, Bs_l, acc);

    const float g = gamma[0];
#pragma unroll
    for (int i = 0; i < 4; ++i) {
        const int mb = m0 + wm + i * 16 + quad * 4;
#pragma unroll
        for (int j = 0; j < 4; ++j) {
            const int nn = n0 + wn + j * 16 + lr;
#pragma unroll
            for (int r = 0; r < 4; ++r) {
                const size_t idx = (size_t)(mb + r) * 4096 + nn;
                out[idx] = g * acc[i][j][r] + 0.5f * (xf[idx] + xl[idx]);
            }
        }
    }
}

// ---------------------------------------------------------------------------
// Row softmax over 4-slice partial sums: A = sm(sum Sfp) + sm(sum Slp),
// bf16 hi only (final GEMM is 2-term), stored SWIZZLED (kpan=32).
__global__ __launch_bounds__(256) void softmax_add4_k(
    const float* __restrict__ Sfp, const float* __restrict__ Slp,
    unsigned short* __restrict__ Ah)
{
    const int row = blockIdx.x;
    const int tid = threadIdx.x;
    __shared__ float red[8];
    const size_t base = (size_t)row * 1024 + tid * 4;
    const size_t SL = (size_t)1024 * 1024;

    float4 vf = *(const float4*)(Sfp + base);
    float4 vl = *(const float4*)(Slp + base);
#pragma unroll
    for (int s = 1; s < 4; ++s) {
        const float4 a = *(const float4*)(Sfp + s * SL + base);
        const float4 b = *(const float4*)(Slp + s * SL + base);
        vf.x += a.x; vf.y += a.y; vf.z += a.z; vf.w += a.w;
        vl.x += b.x; vl.y += b.y; vl.z += b.z; vl.w += b.w;
    }

    float mf = fmaxf(fmaxf(vf.x, vf.y), fmaxf(vf.z, vf.w));
    float ml = fmaxf(fmaxf(vl.x, vl.y), fmaxf(vl.z, vl.w));
#pragma unroll
    for (int off = 32; off; off >>= 1) {
        mf = fmaxf(mf, __shfl_down(mf, off, 64));
        ml = fmaxf(ml, __shfl_down(ml, off, 64));
    }
    const int wave = tid >> 6;
    if ((tid & 63) == 0) { red[wave] = mf; red[4 + wave] = ml; }
    __syncthreads();
    mf = fmaxf(fmaxf(red[0], red[1]), fmaxf(red[2], red[3]));
    ml = fmaxf(fmaxf(red[4], red[5]), fmaxf(red[6], red[7]));
    __syncthreads();

    const float4 ef = make_float4(expf(vf.x - mf), expf(vf.y - mf),
                                  expf(vf.z - mf), expf(vf.w - mf));
    const float4 el = make_float4(expf(vl.x - ml), expf(vl.y - ml),
                                  expf(vl.z - ml), expf(vl.w - ml));
    float sf = ef.x + ef.y + ef.z + ef.w;
    float sl = el.x + el.y + el.z + el.w;
#pragma unroll
    for (int off = 32; off; off >>= 1) {
        sf += __shfl_down(sf, off, 64);
        sl += __shfl_down(sl, off, 64);
    }
    if ((tid & 63) == 0) { red[wave] = sf; red[4 + wave] = sl; }
    __syncthreads();
    sf = red[0] + red[1] + red[2] + red[3];
    sl = red[4] + red[5] + red[6] + red[7];

    const float rf = 1.f / sf, rl = 1.f / sl;
    ushort4 h;
    h.x = f2bf(ef.x * rf + el.x * rl);
    h.y = f2bf(ef.y * rf + el.y * rl);
    h.z = f2bf(ef.z * rf + el.z * rl);
    h.w = f2bf(ef.w * rf + el.w * rl);
    const size_t o = swz(row, tid * 4, 32);   // 4 elems contiguous ((4t)&7 in {0,4})
    *(ushort4*)(Ah + o) = h;
}

__global__ void noop_k(float* p) { if (threadIdx.x == 1024) p[0] = 0.f; }

// ===========================================================================
extern "C" void kernel_launch(void* const* d_in, const int* in_sizes, int n_in,
                              void* d_out, int out_size, void* d_ws, size_t ws_size,
                              hipStream_t stream) {
    (void)in_sizes; (void)n_in; (void)out_size;
    const float* xf  = (const float*)d_in[0];
    const float* xm  = (const float*)d_in[1];
    const float* xl  = (const float*)d_in[2];
    const float* Wq  = (const float*)d_in[3];
    const float* bq  = (const float*)d_in[4];
    const float* Wk1 = (const float*)d_in[5];
    const float* bk1 = (const float*)d_in[6];
    const float* Wk2 = (const float*)d_in[7];
    const float* bk2 = (const float*)d_in[8];
    const float* Wv  = (const float*)d_in[9];
    const float* bv  = (const float*)d_in[10];
    const float* gamma = (const float*)d_in[11];
    float* out = (float*)d_out;

    const size_t MB = 1024 * 1024;
    if (ws_size < 98 * MB) {
        noop_k<<<dim3(1), dim3(64), 0, stream>>>((float*)d_ws);
        return;
    }

    // ---- workspace layout (byte offsets, 98 MB total) ----
    char* p = (char*)d_ws;
    unsigned short* xmT_h = (unsigned short*)(p + 0 * MB);    // [4096][1024] bf16, row-major
    unsigned short* xmT_l = (unsigned short*)(p + 8 * MB);
    unsigned short* xfT_h = (unsigned short*)(p + 16 * MB);
    unsigned short* xfT_l = (unsigned short*)(p + 24 * MB);
    unsigned short* xlT_h = (unsigned short*)(p + 32 * MB);
    unsigned short* xlT_l = (unsigned short*)(p + 40 * MB);
    unsigned short* Wq_h  = (unsigned short*)(p + 48 * MB);   // swizzled
    unsigned short* Wq_l  = (unsigned short*)(p + 49 * MB);
    unsigned short* Wk1_h = (unsigned short*)(p + 50 * MB);
    unsigned short* Wk1_l = (unsigned short*)(p + 51 * MB);
    unsigned short* Wk2_h = (unsigned short*)(p + 52 * MB);
    unsigned short* Wk2_l = (unsigned short*)(p + 53 * MB);
    unsigned short* Wv_h  = (unsigned short*)(p + 54 * MB);
    unsigned short* Wv_l  = (unsigned short*)(p + 56 * MB);
    unsigned short* Q_h   = (unsigned short*)(p + 58 * MB);   // row-major [1024][2048]
    unsigned short* Q_l   = (unsigned short*)(p + 62 * MB);
    unsigned short* Kf_h  = (unsigned short*)(p + 66 * MB);   // swizzled [1024][2048]
    unsigned short* Kf_l  = (unsigned short*)(p + 70 * MB);
    unsigned short* Kl_h  = (unsigned short*)(p + 74 * MB);
    unsigned short* Kl_l  = (unsigned short*)(p + 78 * MB);
    float*          V     = (float*)(p + 82 * MB);            // [1024][4096] f32 (+bias)
    // lifetime-based reuse (launch order: convs -> logits -> V transpose ->
    // softmax -> final):
    float*          Sfp  = (float*)(p + 16 * MB);  // [4][1024][1024] over xfT (dead after convs)
    float*          Slp  = (float*)(p + 32 * MB);  // over xlT
    unsigned short* VT_h = xmT_h;                  // over xmT (dead after convs)
    unsigned short* VT_l = xmT_l;
    unsigned short* Am_h = (unsigned short*)(p + 74 * MB);  // swizzled, over Kl (dead after logits)

    const dim3 blk(256);
    // prep (2 launches): transpose+split the 3 inputs; split the 4 weights
    transpose3_k<<<dim3(128, 32, 3), blk, 0, stream>>>(
        xm, xf, xl, xmT_h, xmT_l, xfT_h, xfT_l, xlT_h, xlT_l);
    weights_split_k<<<dim3(2560), blk, 0, stream>>>(
        Wq, Wk1, Wk2, Wv, Wq_h, Wq_l, Wk1_h, Wk1_l, Wk2_h, Wk2_l, Wv_h, Wv_l);
    // ALL convs, one launch (640 blocks, 128x128 tiles, XCD-swizzled)
    conv_all_k<<<dim3(32, 20), blk, 0, stream>>>(
        Wq_h, Wq_l, Wk1_h, Wk1_l, Wk2_h, Wk2_l, Wv_h, Wv_l,
        xmT_h, xmT_l, xfT_h, xfT_l, xlT_h, xlT_l,
        bq, bk1, bk2, bv,
        Q_h, Q_l, Kf_h, Kf_l, Kl_h, Kl_l, V);
    // logits fused + split-K=4 (512 blocks, 128x128 tiles, XCD z-sliced)
    logits_fused_k<<<dim3(8, 8, 8), blk, 0, stream>>>(
        Kf_h, Kf_l, Kl_h, Kl_l, Q_h, Q_l, Sfp, Slp);
    // VT = transpose+split(V) over dead xmT region
    transpose1_k<<<dim3(128, 32), blk, 0, stream>>>(V, VT_h, VT_l);
    // A = softmax(sum Sfp) + softmax(sum Slp), swizzled bf16-hi over dead Kl
    softmax_add4_k<<<dim3(1024), blk, 0, stream>>>(Sfp, Slp, Am_h);
    // out = gamma*(A (x) VT) + (xf+xl)/2   (256 blocks)
    gemm_final_k<<<dim3(32, 8), blk, 0, stream>>>(
        Am_h, VT_h, VT_l, out, xf, xl, gamma);
}

// Round 12
// 272.295 us; speedup vs baseline: 1.0333x; 1.0219x over previous
//
#include <hip/hip_runtime.h>
#include <math.h>

// ===========================================================================
// CoAtten2: C=1024, H=W=64, HW=4096. Split-bf16 MFMA pipeline (3-term:
// ah*bh + ah*bl + al*bh; final GEMM 2-term with A=probs).
//
// R19 = R18 with the fused-V-transpose WRITE-OUT BUG FIXED:
//   R17/R18 failed with identical absmax 0.756 -> deterministic indexing bug
//   in the fusion (bisection): the write-out used 8 threads/row at 16-channel
//   stride but each wrote only ONE bf16x8 (8 shorts) -> channels c0+8..c0+15
//   of every 16-block never written (half of VT stale). Fix: each thread
//   writes TWO bf16x8 (c0 and c0+8), covering its full 16-channel span.
//   GEMM core unchanged = R16's verified 2-barrier triple-buffered
//   counted-vmcnt pipeline (278 us, absmax 0.015625).
//   split2 inputs bit-identical -> absmax must be exactly 0.015625.
// ===========================================================================

typedef __attribute__((ext_vector_type(8))) short    bf16x8;   // MFMA A/B frag
typedef __attribute__((ext_vector_type(4))) float    f32x4;    // MFMA C/D frag

__device__ __forceinline__ unsigned short f2bf(float x) {
    unsigned u = __float_as_uint(x);
    u += 0x7FFFu + ((u >> 16) & 1u);    // round-to-nearest-even
    return (unsigned short)(u >> 16);
}
__device__ __forceinline__ float bf2f(unsigned short h) {
    return __uint_as_float(((unsigned)h) << 16);
}
__device__ __forceinline__ void split2(float x, unsigned short& h, unsigned short& l) {
    h = f2bf(x);
    l = f2bf(x - bf2f(h));
}

// Frag-major (swizzled) offset for an A-operand matrix [M][K], kpan = K/32.
__device__ __forceinline__ size_t swz(int m, int k, int kpan) {
    return ((size_t)((m >> 4) * kpan + (k >> 5))) * 512
         + (size_t)((((k >> 3) & 3) * 16 + (m & 15)) * 8 + (k & 7));
}

// Async global->LDS DMA, 16B per lane. LDS dest = wave-uniform base + lane*16.
__device__ __forceinline__ void gld16(const unsigned short* g, unsigned short* l) {
    __builtin_amdgcn_global_load_lds(
        (const __attribute__((address_space(1))) unsigned int*)g,
        (__attribute__((address_space(3))) unsigned int*)l,
        16, 0, 0);
}

// 16B global load via inline asm: NOT tracked by the compiler's waitcnt pass.
// Caller is responsible for s_waitcnt vmcnt(N) before reading the result.
__device__ __forceinline__ bf16x8 gload16(const unsigned short* p) {
    bf16x8 r;
    asm volatile("global_load_dwordx4 %0, %1, off"
                 : "=v"(r) : "v"(p) : "memory");
    return r;
}

// Raw workgroup barrier WITHOUT the __syncthreads vmcnt(0) drain.
#define RAW_BARRIER() asm volatile("s_barrier" ::: "memory")

// Exact counted vmem wait: allow N newest ops to stay in flight.
template<int N>
__device__ __forceinline__ void vmwait() {
    asm volatile("s_waitcnt vmcnt(%0)" :: "i"(N) : "memory");
}

// ---------------------------------------------------------------------------
// All-weights split -> SWIZZLED h/l (weights are GEMM-A operands, kpan=32).
__global__ __launch_bounds__(256) void weights_split_k(
    const float* __restrict__ Wq, const float* __restrict__ Wk1,
    const float* __restrict__ Wk2, const float* __restrict__ Wv,
    unsigned short* __restrict__ Wqh, unsigned short* __restrict__ Wql,
    unsigned short* __restrict__ Wk1h, unsigned short* __restrict__ Wk1l,
    unsigned short* __restrict__ Wk2h, unsigned short* __restrict__ Wk2l,
    unsigned short* __restrict__ Wvh, unsigned short* __restrict__ Wvl)
{
    const int gi = blockIdx.x;
    const float* src; unsigned short *H, *L; int base;
    if (gi < 512)       { src = Wq;  H = Wqh;  L = Wql;  base = gi; }
    else if (gi < 1024) { src = Wk1; H = Wk1h; L = Wk1l; base = gi - 512; }
    else if (gi < 1536) { src = Wk2; H = Wk2h; L = Wk2l; base = gi - 1024; }
    else                { src = Wv;  H = Wvh;  L = Wvl;  base = gi - 1536; }
    const size_t i = (size_t)base * 1024 + threadIdx.x * 4;
    const int m = (int)(i >> 10);
    const int k = (int)(i & 1023);
    const float4 v = *(const float4*)(src + i);
    ushort4 h, l;
    split2(v.x, h.x, l.x); split2(v.y, h.y, l.y);
    split2(v.z, h.z, l.z); split2(v.w, h.w, l.w);
    const size_t o = swz(m, k, 32);      // k&7 in {0,4}: 4 elems contiguous
    *(ushort4*)(H + o) = h;
    *(ushort4*)(L + o) = l;
}

// ---------------------------------------------------------------------------
// Transpose + split for the 3 inputs in one launch (z selects which).
__global__ __launch_bounds__(256) void transpose3_k(
    const float* __restrict__ x0, const float* __restrict__ x1,
    const float* __restrict__ x2,
    unsigned short* __restrict__ t0h, unsigned short* __restrict__ t0l,
    unsigned short* __restrict__ t1h, unsigned short* __restrict__ t1l,
    unsigned short* __restrict__ t2h, unsigned short* __restrict__ t2l)
{
    const float* X; unsigned short *Th, *Tl;
    if (blockIdx.z == 0)      { X = x0; Th = t0h; Tl = t0l; }
    else if (blockIdx.z == 1) { X = x1; Th = t1h; Tl = t1l; }
    else                      { X = x2; Th = t2h; Tl = t2l; }

    __shared__ float t[32 * 33];
    const int tid = threadIdx.x;
    const int c0 = blockIdx.y * 32;
    const int p0 = blockIdx.x * 32;

    const int cl = tid >> 3;
    const int p4 = (tid & 7) * 4;
    const float4 v = *(const float4*)(X + (size_t)(c0 + cl) * 4096 + p0 + p4);
    t[(p4 + 0) * 33 + cl] = v.x;
    t[(p4 + 1) * 33 + cl] = v.y;
    t[(p4 + 2) * 33 + cl] = v.z;
    t[(p4 + 3) * 33 + cl] = v.w;
    __syncthreads();

    const int pl = tid >> 3;
    const int c4 = (tid & 7) * 4;
    ushort4 h, l;
    split2(t[pl * 33 + c4 + 0], h.x, l.x);
    split2(t[pl * 33 + c4 + 1], h.y, l.y);
    split2(t[pl * 33 + c4 + 2], h.z, l.z);
    split2(t[pl * 33 + c4 + 3], h.w, l.w);
    const size_t o = (size_t)(p0 + pl) * 1024 + c0 + c4;
    *(ushort4*)(Th + o) = h;
    *(ushort4*)(Tl + o) = l;
}

// ---------------------------------------------------------------------------
// GEMM core v8 (VERIFIED in R16): counted-vmcnt pipeline, B prefetch depth 2
// (triple-buffered LDS), A register prefetch depth 1. A loads via inline asm.
// Step s: BAR1; issue A(s+1), D(s+2); vmcnt keeps {A(s+1),D(s+1),D(s+2)};
// BAR2; ds_read B(s) + MFMA. Two barriers per step.
// Tile 128 x (32*NJ), BK=32, 4 waves 2x2, wave 64 x (16*NJ) = 4xNJ MFMA tiles.
// TERMS=3: ah*bh + ah*bl + al*bh.  TERMS=2: ah*bh + ah*bl.
template<int TERMS, int NJ>
__device__ __forceinline__ void gemm_core(
    const unsigned short* __restrict__ Ah, const unsigned short* __restrict__ Al,
    const unsigned short* __restrict__ Bh, const unsigned short* __restrict__ Bl,
    int ldkB, int kpanA, int kbeg, int kend, int m0, int n0,
    unsigned short* Bs_h, unsigned short* Bs_l,   // each [3][32*NJ*32]
    f32x4 (&acc)[4][NJ])
{
    const int tid  = threadIdx.x;
    const int lane = tid & 63;
    const int wv   = tid >> 6;
    const int wm   = (wv >> 1) * 64;
    const int wn   = (wv & 1) * (16 * NJ);
    const int lr   = lane & 15;
    const int quad = lane >> 4;
    const int BUFE = 1024 * NJ;            // elems per h/l LDS buffer
    constexpr int AOPS = (TERMS == 3 ? 8 : 4);
    // steady-state in-flight kept: A(s+1) + D(s+1) + D(s+2)
    constexpr int VM_FULL = AOPS + NJ + NJ;
    // tail (s+2==nsteps): keep A(s+1) + D(s+1)
    constexpr int VM_MID  = AOPS + NJ;

    // --- B staging: waves {0,1} -> Bs_h, waves {2,3} -> Bs_l; NJ insts/wave ---
    const unsigned short* gsrc = (wv < 2) ? Bh : Bl;
    unsigned short* ldst = (wv < 2) ? Bs_h : Bs_l;
    const int tt0  = (wv & 1) * NJ;
    const int lrow = lane >> 2;
    const int gseg = ((lane & 3) - ((lane >> 3) & 3)) & 3;  // store-side swizzle
    const size_t bstep = (size_t)16 * (size_t)ldkB;         // 16 B-rows
    const unsigned short* gp0 =
        gsrc + (size_t)(n0 + tt0 * 16 + lrow) * ldkB + kbeg + gseg * 8;

    // --- A frag base: swizzled layout -> contiguous lane*16B loads ---
    const int pk0 = kbeg >> 5;
    const size_t astr  = (size_t)kpanA * 512;               // per 16-row panel
    const size_t abase = (size_t)((m0 + wm) >> 4) * astr + (size_t)pk0 * 512
                       + (size_t)lane * 8;
    const unsigned short* ap0 = Ah + abase;
    const unsigned short* al0 = (TERMS == 3) ? (Al + abase) : nullptr;

    const int rdseg = (quad + (lr >> 1)) & 3;               // LDS read-side swizzle

    const int nsteps = (kend - kbeg) >> 5;   // conv/final 32, logits 16 (even)

    // prologue (FIFO order matters for the vmcnt ladder):
    //   DMA(0)->buf0, A(0)->regs, DMA(1)->buf1
#pragma unroll
    for (int u = 0; u < NJ; ++u)
        gld16(gp0 + (size_t)u * bstep, ldst + 0 * BUFE + (tt0 + u) * 512);

    bf16x8 cah[4], cal[4], nah[4], nal[4];
#pragma unroll
    for (int i = 0; i < 4; ++i) {
        cah[i] = gload16(ap0 + (size_t)i * astr);
        if (TERMS == 3) cal[i] = gload16(al0 + (size_t)i * astr);
    }
#pragma unroll
    for (int u = 0; u < NJ; ++u)
        gld16(gp0 + (size_t)u * bstep + 32, ldst + 1 * BUFE + (tt0 + u) * 512);

    int br = 0;            // read buffer for current step  (s % 3)
    int bw = 2;            // write buffer for step s+2     ((s+2) % 3)

    // One K-step:
    //   BAR1: all waves done reading buf bw (last read at step s-1).
    //   issue A(s+1) asm loads; issue DMA(s+2) into buf bw.
    //   vmcnt(N): retires A(s)+D(s); keeps {A(s+1), D(s+1), D(s+2)}.
    //   BAR2 + sched_barrier: all waves' D(s) LDS writes visible; no hoist.
    //   ds_read B(s) from buf br (compiler lgkmcnt), MFMA on A(s) regs.
#define GSTEP(S, CH, CL, NH, NL)                                              \
    {                                                                         \
        RAW_BARRIER();                                                        \
        const bool hasA = (S) + 1 < nsteps;                                   \
        const bool hasD = (S) + 2 < nsteps;                                   \
        if (hasA) {                                                           \
            const size_t aoff = (size_t)((S) + 1) * 512;                      \
            _Pragma("unroll")                                                 \
            for (int i = 0; i < 4; ++i) {                                     \
                NH[i] = gload16(ap0 + (size_t)i * astr + aoff);               \
                if (TERMS == 3)                                               \
                    NL[i] = gload16(al0 + (size_t)i * astr + aoff);           \
            }                                                                 \
        }                                                                     \
        if (hasD) {                                                           \
            const size_t goff = (size_t)((S) + 2) * 32;                       \
            unsigned short* dst = ldst + bw * BUFE;                           \
            _Pragma("unroll")                                                 \
            for (int u = 0; u < NJ; ++u)                                      \
                gld16(gp0 + (size_t)u * bstep + goff, dst + (tt0 + u) * 512); \
            vmwait<VM_FULL>();                                                \
        } else if (hasA) {                                                    \
            vmwait<VM_MID>();                                                 \
        } else {                                                              \
            vmwait<0>();                                                      \
        }                                                                     \
        RAW_BARRIER();                                                        \
        __builtin_amdgcn_sched_barrier(0);                                    \
        const int rbase = br * BUFE + (wn + lr) * 32 + rdseg * 8;             \
        _Pragma("unroll")                                                     \
        for (int j = 0; j < NJ; ++j) {                                        \
            const bf16x8 bh = *(const bf16x8*)(Bs_h + rbase + j * 512);       \
            const bf16x8 bl = *(const bf16x8*)(Bs_l + rbase + j * 512);       \
            _Pragma("unroll")                                                 \
            for (int i = 0; i < 4; ++i) {                                     \
                acc[i][j] = __builtin_amdgcn_mfma_f32_16x16x32_bf16(          \
                    CH[i], bh, acc[i][j], 0, 0, 0);                           \
                acc[i][j] = __builtin_amdgcn_mfma_f32_16x16x32_bf16(          \
                    CH[i], bl, acc[i][j], 0, 0, 0);                           \
                if (TERMS == 3)                                               \
                    acc[i][j] = __builtin_amdgcn_mfma_f32_16x16x32_bf16(      \
                        CL[i], bh, acc[i][j], 0, 0, 0);                       \
            }                                                                 \
        }                                                                     \
        br = (br == 2) ? 0 : br + 1;                                          \
        bw = (bw == 2) ? 0 : bw + 1;                                          \
    }

    for (int s = 0; s < nsteps; s += 2) {
        GSTEP(s,     cah, cal, nah, nal);
        GSTEP(s + 1, nah, nal, cah, cal);
    }
#undef GSTEP
    // NOTE: no trailing barrier — epilogues that reuse LDS must __syncthreads.
}

#define GEMM_PROLOGUE(NJ_)                                              \
    __shared__ __align__(16) unsigned short Bs_h[3 * 1024 * (NJ_)];     \
    __shared__ __align__(16) unsigned short Bs_l[3 * 1024 * (NJ_)];     \
    f32x4 acc[4][(NJ_)];                                                \
    _Pragma("unroll") for (int i = 0; i < 4; ++i)                       \
    _Pragma("unroll") for (int j = 0; j < (NJ_); ++j)                   \
    _Pragma("unroll") for (int r = 0; r < 4; ++r) acc[i][j][r] = 0.f;   \
    const int lane = threadIdx.x & 63;                                  \
    const int wv   = threadIdx.x >> 6;                                  \
    const int wm   = (wv >> 1) * 64;                                    \
    const int wn   = (wv & 1) * (16 * (NJ_));                           \
    const int lr   = lane & 15;                                         \
    const int quad = lane >> 4;                                         \
    (void)lane; (void)wv; (void)wm; (void)wn;

// ---------------------------------------------------------------------------
// ALL FOUR convs, one launch. 128x128 tiles (NJ=4). 640 blocks:
// mt (0..19) x nx (0..31); mt partitions [Wq(4) | Wk1(4) | Wk2(4) | Wv(8)].
// XCD-swizzled (640 % 8 == 0, bijective): XCD d owns wg in [80d, 80d+80).
// mode 2 (V conv) writes VT h/l DIRECTLY via LDS slab transpose (fused);
// __syncthreads() first (core has no trailing barrier).
__global__ __launch_bounds__(256, 2) void conv_all_k(
    const unsigned short* __restrict__ Wqh, const unsigned short* __restrict__ Wql,
    const unsigned short* __restrict__ Wk1h, const unsigned short* __restrict__ Wk1l,
    const unsigned short* __restrict__ Wk2h, const unsigned short* __restrict__ Wk2l,
    const unsigned short* __restrict__ Wvh, const unsigned short* __restrict__ Wvl,
    const unsigned short* __restrict__ xmTh, const unsigned short* __restrict__ xmTl,
    const unsigned short* __restrict__ xfTh, const unsigned short* __restrict__ xfTl,
    const unsigned short* __restrict__ xlTh, const unsigned short* __restrict__ xlTl,
    const float* __restrict__ bq, const float* __restrict__ bk1,
    const float* __restrict__ bk2, const float* __restrict__ bv,
    unsigned short* __restrict__ Qh, unsigned short* __restrict__ Ql,
    unsigned short* __restrict__ Kfh, unsigned short* __restrict__ Kfl,
    unsigned short* __restrict__ Klh, unsigned short* __restrict__ Kll,
    unsigned short* __restrict__ VTh, unsigned short* __restrict__ VTl)
{
    GEMM_PROLOGUE(4);
    // XCD-aware bijective swizzle: XCD d owns wg in [80d, 80d+80)
    const int lid = blockIdx.y * 32 + blockIdx.x;        // 0..639
    const int wg  = (lid & 7) * 80 + (lid >> 3);
    const int mt  = wg >> 5;                             // 0..19
    const int n0  = (wg & 31) * 128;

    const unsigned short *Ah, *Al, *Bh, *Bl;
    const float* bias;
    unsigned short *Ch = nullptr, *Cl = nullptr;
    int mloc, mode;
    if (mt < 4) {
        Ah = Wqh;  Al = Wql;  Bh = xmTh; Bl = xmTl; bias = bq;
        Ch = Qh;   Cl = Ql;   mloc = mt * 128;        mode = 0;
    } else if (mt < 8) {
        Ah = Wk1h; Al = Wk1l; Bh = xfTh; Bl = xfTl; bias = bk1;
        Ch = Kfh;  Cl = Kfl;  mloc = (mt - 4) * 128;  mode = 1;
    } else if (mt < 12) {
        Ah = Wk2h; Al = Wk2l; Bh = xlTh; Bl = xlTl; bias = bk2;
        Ch = Klh;  Cl = Kll;  mloc = (mt - 8) * 128;  mode = 1;
    } else {
        Ah = Wvh;  Al = Wvl;  Bh = xmTh; Bl = xmTl; bias = bv;
        mloc = (mt - 12) * 128;                       mode = 2;
    }

    gemm_core<3, 4>(Ah, Al, Bh, Bl, 1024, 32, 0, 1024, mloc, n0, Bs_h, Bs_l, acc);

    if (mode == 2) {
        // Fused transpose: sync first (core has no trailing barrier), then
        // stage 32-pixel-row slabs [32][136] in dead B LDS, write VT[p][c]
        // h/l coalesced. Each thread owns 16 channels = TWO bf16x8 writes
        // (R17/R18 bug: only one was written -> half of VT stale).
        __syncthreads();
        unsigned short (*Sh)[136] = (unsigned short (*)[136])Bs_h;
        unsigned short (*Sl)[136] = (unsigned short (*)[136])Bs_l;
        const int myhalf = (wv & 1);          // wn==64 waves own p_local>=64
#pragma unroll
        for (int sb = 0; sb < 4; ++sb) {
            if ((sb >> 1) == myhalf) {
                const int jbase = (sb & 1) * 2;
#pragma unroll
                for (int jj = 0; jj < 2; ++jj) {
                    const int j = jbase + jj;
                    const int prow = jj * 16 + lr;
#pragma unroll
                    for (int i = 0; i < 4; ++i) {
#pragma unroll
                        for (int r = 0; r < 4; ++r) {
                            const int c = wm + i * 16 + quad * 4 + r;
                            const float v = acc[i][j][r] + bias[mloc + c];
                            unsigned short h, l;
                            split2(v, h, l);
                            Sh[prow][c] = h;
                            Sl[prow][c] = l;
                        }
                    }
                }
            }
            __syncthreads();
            {
                const int pl2 = threadIdx.x >> 3;         // 0..31
                const int c0  = (threadIdx.x & 7) * 16;   // 0..112 (16-ch span)
                const size_t ob = (size_t)(n0 + sb * 32 + pl2) * 1024 + mloc + c0;
                *(bf16x8*)(VTh + ob)     = *(const bf16x8*)&Sh[pl2][c0];
                *(bf16x8*)(VTh + ob + 8) = *(const bf16x8*)&Sh[pl2][c0 + 8];
                *(bf16x8*)(VTl + ob)     = *(const bf16x8*)&Sl[pl2][c0];
                *(bf16x8*)(VTl + ob + 8) = *(const bf16x8*)&Sl[pl2][c0 + 8];
            }
            __syncthreads();
        }
        return;
    }

#pragma unroll
    for (int i = 0; i < 4; ++i) {
        const int mb = mloc + wm + i * 16 + quad * 4;
#pragma unroll
        for (int j = 0; j < 4; ++j) {
            const int nn = n0 + wn + j * 16 + lr;
#pragma unroll
            for (int r = 0; r < 4; ++r) {
                const float v = acc[i][j][r] + bias[mb + r];
                if (mode == 0) {
                    unsigned short h, l;
                    split2(v, h, l);
                    const size_t idx = (size_t)(mb + r) * 4096 + nn;
                    Ch[idx] = h;
                    Cl[idx] = l;
                } else {
                    // swizzled store for logits-A view [1024][2048]
                    const int m2 = ((mb + r) << 1) | (nn >> 11);
                    const int k2 = nn & 2047;
                    const size_t o = swz(m2, k2, 64);
                    unsigned short h, l;
                    split2(v, h, l);
                    Ch[o] = h;
                    Cl[o] = l;
                }
            }
        }
    }
}

// ---------------------------------------------------------------------------
// Fused logits, split-K, 128x128 tiles (NJ=4). 512 blocks:
// z = which(f/l)*4 + kslice(0..3), m-tile(0..7), n-tile(0..7).
// XCD-swizzled so each XCD owns one full z-slice (A 2MB + Q 2MB fit 4MB L2).
__global__ __launch_bounds__(256, 2) void logits_fused_k(
    const unsigned short* __restrict__ Kfh, const unsigned short* __restrict__ Kfl,
    const unsigned short* __restrict__ Klh, const unsigned short* __restrict__ Kll,
    const unsigned short* __restrict__ Qh, const unsigned short* __restrict__ Ql,
    float* __restrict__ Sfp, float* __restrict__ Slp)
{
    GEMM_PROLOGUE(4);
    const int lid = (blockIdx.z * 8 + blockIdx.y) * 8 + blockIdx.x;  // 0..511
    const int wg  = (lid & 7) * 64 + (lid >> 3);
    const int bx  = wg & 7;
    const int by  = (wg >> 3) & 7;
    const int bz  = wg >> 6;

    const int which = bz >> 2;
    const int slice = bz & 3;
    const unsigned short* Ah = which ? Klh : Kfh;
    const unsigned short* Al = which ? Kll : Kfl;
    float* out = (which ? Slp : Sfp) + (size_t)slice * 1024 * 1024;
    const int m0 = by * 128;
    const int n0 = bx * 128;

    gemm_core<3, 4>(Ah, Al, Qh, Ql, 2048, 64, slice * 512, slice * 512 + 512,
                    m0, n0, Bs_h, Bs_l, acc);

#pragma unroll
    for (int i = 0; i < 4; ++i) {
        const int mb = m0 + wm + i * 16 + quad * 4;
#pragma unroll
        for (int j = 0; j < 4; ++j) {
            const int nn = n0 + wn + j * 16 + lr;
#pragma unroll
            for (int r = 0; r < 4; ++r)
                out[(size_t)(mb + r) * 1024 + nn] = acc[i][j][r];
        }
    }
}

// ---------------------------------------------------------------------------
// Final: out = gamma*(A (x) VT) + 0.5*(xf+xl). A = Am swizzled (kpan=32),
// B = VT row-major ldk=1024. NJ=4, 256 blocks. 2-term.
__global__ __launch_bounds__(256, 2) void gemm_final_k(
    const unsigned short* __restrict__ Amh,
    const unsigned short* __restrict__ VTh, const unsigned short* __restrict__ VTl,
    float* __restrict__ out,
    const float* __restrict__ xf, const float* __restrict__ xl,
    const float* __restrict__ gamma)
{
    GEMM_PROLOGUE(4);
    const int m0 = blockIdx.y * 128;
    const int n0 = blockIdx.x * 128;

    gemm_core<2, 4>(Amh, nullptr, VTh, VTl, 1024, 32, 0, 1024, m0, n0,
                    Bs_h, Bs_l, acc);

    const float g = gamma[0];
#pragma unroll
    for (int i = 0; i < 4; ++i) {
        const int mb = m0 + wm + i * 16 + quad * 4;
#pragma unroll
        for (int j = 0; j < 4; ++j) {
            const int nn = n0 + wn + j * 16 + lr;
#pragma unroll
            for (int r = 0; r < 4; ++r) {
                const size_t idx = (size_t)(mb + r) * 4096 + nn;
                out[idx] = g * acc[i][j][r] + 0.5f * (xf[idx] + xl[idx]);
            }
        }
    }
}

// ---------------------------------------------------------------------------
// Row softmax over 4-slice partial sums: A = sm(sum Sfp) + sm(sum Slp),
// bf16 hi only (final GEMM is 2-term), stored SWIZZLED (kpan=32).
__global__ __launch_bounds__(256) void softmax_add4_k(
    const float* __restrict__ Sfp, const float* __restrict__ Slp,
    unsigned short* __restrict__ Ah)
{
    const int row = blockIdx.x;
    const int tid = threadIdx.x;
    __shared__ float red[8];
    const size_t base = (size_t)row * 1024 + tid * 4;
    const size_t SL = (size_t)1024 * 1024;

    float4 vf = *(const float4*)(Sfp + base);
    float4 vl = *(const float4*)(Slp + base);
#pragma unroll
    for (int s = 1; s < 4; ++s) {
        const float4 a = *(const float4*)(Sfp + s * SL + base);
        const float4 b = *(const float4*)(Slp + s * SL + base);
        vf.x += a.x; vf.y += a.y; vf.z += a.z; vf.w += a.w;
        vl.x += b.x; vl.y += b.y; vl.z += b.z; vl.w += b.w;
    }

    float mf = fmaxf(fmaxf(vf.x, vf.y), fmaxf(vf.z, vf.w));
    float ml = fmaxf(fmaxf(vl.x, vl.y), fmaxf(vl.z, vl.w));
#pragma unroll
    for (int off = 32; off; off >>= 1) {
        mf = fmaxf(mf, __shfl_down(mf, off, 64));
        ml = fmaxf(ml, __shfl_down(ml, off, 64));
    }
    const int wave = tid >> 6;
    if ((tid & 63) == 0) { red[wave] = mf; red[4 + wave] = ml; }
    __syncthreads();
    mf = fmaxf(fmaxf(red[0], red[1]), fmaxf(red[2], red[3]));
    ml = fmaxf(fmaxf(red[4], red[5]), fmaxf(red[6], red[7]));
    __syncthreads();

    const float4 ef = make_float4(expf(vf.x - mf), expf(vf.y - mf),
                                  expf(vf.z - mf), expf(vf.w - mf));
    const float4 el = make_float4(expf(vl.x - ml), expf(vl.y - ml),
                                  expf(vl.z - ml), expf(vl.w - ml));
    float sf = ef.x + ef.y + ef.z + ef.w;
    float sl = el.x + el.y + el.z + el.w;
#pragma unroll
    for (int off = 32; off; off >>= 1) {
        sf += __shfl_down(sf, off, 64);
        sl += __shfl_down(sl, off, 64);
    }
    if ((tid & 63) == 0) { red[wave] = sf; red[4 + wave] = sl; }
    __syncthreads();
    sf = red[0] + red[1] + red[2] + red[3];
    sl = red[4] + red[5] + red[6] + red[7];

    const float rf = 1.f / sf, rl = 1.f / sl;
    ushort4 h;
    h.x = f2bf(ef.x * rf + el.x * rl);
    h.y = f2bf(ef.y * rf + el.y * rl);
    h.z = f2bf(ef.z * rf + el.z * rl);
    h.w = f2bf(ef.w * rf + el.w * rl);
    const size_t o = swz(row, tid * 4, 32);   // 4 elems contiguous ((4t)&7 in {0,4})
    *(ushort4*)(Ah + o) = h;
}

__global__ void noop_k(float* p) { if (threadIdx.x == 1024) p[0] = 0.f; }

// ===========================================================================
extern "C" void kernel_launch(void* const* d_in, const int* in_sizes, int n_in,
                              void* d_out, int out_size, void* d_ws, size_t ws_size,
                              hipStream_t stream) {
    (void)in_sizes; (void)n_in; (void)out_size;
    const float* xf  = (const float*)d_in[0];
    const float* xm  = (const float*)d_in[1];
    const float* xl  = (const float*)d_in[2];
    const float* Wq  = (const float*)d_in[3];
    const float* bq  = (const float*)d_in[4];
    const float* Wk1 = (const float*)d_in[5];
    const float* bk1 = (const float*)d_in[6];
    const float* Wk2 = (const float*)d_in[7];
    const float* bk2 = (const float*)d_in[8];
    const float* Wv  = (const float*)d_in[9];
    const float* bv  = (const float*)d_in[10];
    const float* gamma = (const float*)d_in[11];
    float* out = (float*)d_out;

    const size_t MB = 1024 * 1024;
    if (ws_size < 98 * MB) {
        noop_k<<<dim3(1), dim3(64), 0, stream>>>((float*)d_ws);
        return;
    }

    // ---- workspace layout (byte offsets, 98 MB total) ----
    char* p = (char*)d_ws;
    unsigned short* xmT_h = (unsigned short*)(p + 0 * MB);    // [4096][1024] bf16, row-major
    unsigned short* xmT_l = (unsigned short*)(p + 8 * MB);
    unsigned short* xfT_h = (unsigned short*)(p + 16 * MB);
    unsigned short* xfT_l = (unsigned short*)(p + 24 * MB);
    unsigned short* xlT_h = (unsigned short*)(p + 32 * MB);
    unsigned short* xlT_l = (unsigned short*)(p + 40 * MB);
    unsigned short* Wq_h  = (unsigned short*)(p + 48 * MB);   // swizzled
    unsigned short* Wq_l  = (unsigned short*)(p + 49 * MB);
    unsigned short* Wk1_h = (unsigned short*)(p + 50 * MB);
    unsigned short* Wk1_l = (unsigned short*)(p + 51 * MB);
    unsigned short* Wk2_h = (unsigned short*)(p + 52 * MB);
    unsigned short* Wk2_l = (unsigned short*)(p + 53 * MB);
    unsigned short* Wv_h  = (unsigned short*)(p + 54 * MB);
    unsigned short* Wv_l  = (unsigned short*)(p + 56 * MB);
    unsigned short* Q_h   = (unsigned short*)(p + 58 * MB);   // row-major [1024][2048]
    unsigned short* Q_l   = (unsigned short*)(p + 62 * MB);
    unsigned short* Kf_h  = (unsigned short*)(p + 66 * MB);   // swizzled [1024][2048]
    unsigned short* Kf_l  = (unsigned short*)(p + 70 * MB);
    unsigned short* Kl_h  = (unsigned short*)(p + 74 * MB);
    unsigned short* Kl_l  = (unsigned short*)(p + 78 * MB);
    unsigned short* VT_h  = (unsigned short*)(p + 82 * MB);   // [4096][1024] bf16 (fused out of conv)
    unsigned short* VT_l  = (unsigned short*)(p + 90 * MB);
    // lifetime-based reuse (launch order: convs -> logits -> softmax -> final):
    float*          Sfp  = (float*)(p + 16 * MB);  // [4][1024][1024] over xfT (dead after convs)
    float*          Slp  = (float*)(p + 32 * MB);  // over xlT
    unsigned short* Am_h = (unsigned short*)(p + 74 * MB);  // swizzled, over Kl (dead after logits)

    const dim3 blk(256);
    // prep (2 launches): transpose+split the 3 inputs; split the 4 weights
    transpose3_k<<<dim3(128, 32, 3), blk, 0, stream>>>(
        xm, xf, xl, xmT_h, xmT_l, xfT_h, xfT_l, xlT_h, xlT_l);
    weights_split_k<<<dim3(2560), blk, 0, stream>>>(
        Wq, Wk1, Wk2, Wv, Wq_h, Wq_l, Wk1_h, Wk1_l, Wk2_h, Wk2_l, Wv_h, Wv_l);
    // ALL convs, one launch (640 blocks); V conv writes VT h/l directly
    conv_all_k<<<dim3(32, 20), blk, 0, stream>>>(
        Wq_h, Wq_l, Wk1_h, Wk1_l, Wk2_h, Wk2_l, Wv_h, Wv_l,
        xmT_h, xmT_l, xfT_h, xfT_l, xlT_h, xlT_l,
        bq, bk1, bk2, bv,
        Q_h, Q_l, Kf_h, Kf_l, Kl_h, Kl_l, VT_h, VT_l);
    // logits fused + split-K=4 (512 blocks, XCD z-sliced)
    logits_fused_k<<<dim3(8, 8, 8), blk, 0, stream>>>(
        Kf_h, Kf_l, Kl_h, Kl_l, Q_h, Q_l, Sfp, Slp);
    // A = softmax(sum Sfp) + softmax(sum Slp), swizzled bf16-hi over dead Kl
    softmax_add4_k<<<dim3(1024), blk, 0, stream>>>(Sfp, Slp, Am_h);
    // out = gamma*(A (x) VT) + (xf+xl)/2   (256 blocks)
    gemm_final_k<<<dim3(32, 8), blk, 0, stream>>>(
        Am_h, VT_h, VT_l, out, xf, xl, gamma);
}

// Round 13
// 268.705 us; speedup vs baseline: 1.0471x; 1.0134x over previous
//
#include <hip/hip_runtime.h>
#include <math.h>

// ===========================================================================
// CoAtten2: C=1024, H=W=64, HW=4096. Split-bf16 MFMA pipeline (3-term:
// ah*bh + ah*bl + al*bh; final GEMM 2-term with A=probs).
//
// R20 = R19 (PASSED, 272.3 us, absmax 0.015625: fused V-transpose verified)
// + SINGLE-BARRIER K-step as the ONLY change (completing R17's interrupted
// experiment — its failure is now fully attributed to the fusion bug):
//   Step s: { issue A(s+1), D(s+2)->buf[(s+2)%3]; vmcnt keeps {A(s+1),D(s+2)}
//   (retires A(s),D(s),D(s+1)); sched_barrier; ds_read B(s) + MFMA;
//   s_barrier }. One barrier per step (was two).
//   Safety: D(s) retired at step s-1's vmwait + published by its end-of-step
//   barrier; buf[(s+2)%3]'s last reads precede that same barrier.
//   Mechanism (m233): 2-phase stage+wait+barrier serialization ~72% of step;
//   halving barrier count lets MFMA run right after the vmwait.
//   absmax must stay exactly 0.015625 (any change = race -> permanent revert
//   to the 2-barrier core).
// ===========================================================================

typedef __attribute__((ext_vector_type(8))) short    bf16x8;   // MFMA A/B frag
typedef __attribute__((ext_vector_type(4))) float    f32x4;    // MFMA C/D frag

__device__ __forceinline__ unsigned short f2bf(float x) {
    unsigned u = __float_as_uint(x);
    u += 0x7FFFu + ((u >> 16) & 1u);    // round-to-nearest-even
    return (unsigned short)(u >> 16);
}
__device__ __forceinline__ float bf2f(unsigned short h) {
    return __uint_as_float(((unsigned)h) << 16);
}
__device__ __forceinline__ void split2(float x, unsigned short& h, unsigned short& l) {
    h = f2bf(x);
    l = f2bf(x - bf2f(h));
}

// Frag-major (swizzled) offset for an A-operand matrix [M][K], kpan = K/32.
__device__ __forceinline__ size_t swz(int m, int k, int kpan) {
    return ((size_t)((m >> 4) * kpan + (k >> 5))) * 512
         + (size_t)((((k >> 3) & 3) * 16 + (m & 15)) * 8 + (k & 7));
}

// Async global->LDS DMA, 16B per lane. LDS dest = wave-uniform base + lane*16.
__device__ __forceinline__ void gld16(const unsigned short* g, unsigned short* l) {
    __builtin_amdgcn_global_load_lds(
        (const __attribute__((address_space(1))) unsigned int*)g,
        (__attribute__((address_space(3))) unsigned int*)l,
        16, 0, 0);
}

// 16B global load via inline asm: NOT tracked by the compiler's waitcnt pass.
// Caller is responsible for s_waitcnt vmcnt(N) before reading the result.
__device__ __forceinline__ bf16x8 gload16(const unsigned short* p) {
    bf16x8 r;
    asm volatile("global_load_dwordx4 %0, %1, off"
                 : "=v"(r) : "v"(p) : "memory");
    return r;
}

// Raw workgroup barrier WITHOUT the __syncthreads vmcnt(0) drain.
#define RAW_BARRIER() asm volatile("s_barrier" ::: "memory")

// Exact counted vmem wait: allow N newest ops to stay in flight.
template<int N>
__device__ __forceinline__ void vmwait() {
    asm volatile("s_waitcnt vmcnt(%0)" :: "i"(N) : "memory");
}

// ---------------------------------------------------------------------------
// All-weights split -> SWIZZLED h/l (weights are GEMM-A operands, kpan=32).
__global__ __launch_bounds__(256) void weights_split_k(
    const float* __restrict__ Wq, const float* __restrict__ Wk1,
    const float* __restrict__ Wk2, const float* __restrict__ Wv,
    unsigned short* __restrict__ Wqh, unsigned short* __restrict__ Wql,
    unsigned short* __restrict__ Wk1h, unsigned short* __restrict__ Wk1l,
    unsigned short* __restrict__ Wk2h, unsigned short* __restrict__ Wk2l,
    unsigned short* __restrict__ Wvh, unsigned short* __restrict__ Wvl)
{
    const int gi = blockIdx.x;
    const float* src; unsigned short *H, *L; int base;
    if (gi < 512)       { src = Wq;  H = Wqh;  L = Wql;  base = gi; }
    else if (gi < 1024) { src = Wk1; H = Wk1h; L = Wk1l; base = gi - 512; }
    else if (gi < 1536) { src = Wk2; H = Wk2h; L = Wk2l; base = gi - 1024; }
    else                { src = Wv;  H = Wvh;  L = Wvl;  base = gi - 1536; }
    const size_t i = (size_t)base * 1024 + threadIdx.x * 4;
    const int m = (int)(i >> 10);
    const int k = (int)(i & 1023);
    const float4 v = *(const float4*)(src + i);
    ushort4 h, l;
    split2(v.x, h.x, l.x); split2(v.y, h.y, l.y);
    split2(v.z, h.z, l.z); split2(v.w, h.w, l.w);
    const size_t o = swz(m, k, 32);      // k&7 in {0,4}: 4 elems contiguous
    *(ushort4*)(H + o) = h;
    *(ushort4*)(L + o) = l;
}

// ---------------------------------------------------------------------------
// Transpose + split for the 3 inputs in one launch (z selects which).
__global__ __launch_bounds__(256) void transpose3_k(
    const float* __restrict__ x0, const float* __restrict__ x1,
    const float* __restrict__ x2,
    unsigned short* __restrict__ t0h, unsigned short* __restrict__ t0l,
    unsigned short* __restrict__ t1h, unsigned short* __restrict__ t1l,
    unsigned short* __restrict__ t2h, unsigned short* __restrict__ t2l)
{
    const float* X; unsigned short *Th, *Tl;
    if (blockIdx.z == 0)      { X = x0; Th = t0h; Tl = t0l; }
    else if (blockIdx.z == 1) { X = x1; Th = t1h; Tl = t1l; }
    else                      { X = x2; Th = t2h; Tl = t2l; }

    __shared__ float t[32 * 33];
    const int tid = threadIdx.x;
    const int c0 = blockIdx.y * 32;
    const int p0 = blockIdx.x * 32;

    const int cl = tid >> 3;
    const int p4 = (tid & 7) * 4;
    const float4 v = *(const float4*)(X + (size_t)(c0 + cl) * 4096 + p0 + p4);
    t[(p4 + 0) * 33 + cl] = v.x;
    t[(p4 + 1) * 33 + cl] = v.y;
    t[(p4 + 2) * 33 + cl] = v.z;
    t[(p4 + 3) * 33 + cl] = v.w;
    __syncthreads();

    const int pl = tid >> 3;
    const int c4 = (tid & 7) * 4;
    ushort4 h, l;
    split2(t[pl * 33 + c4 + 0], h.x, l.x);
    split2(t[pl * 33 + c4 + 1], h.y, l.y);
    split2(t[pl * 33 + c4 + 2], h.z, l.z);
    split2(t[pl * 33 + c4 + 3], h.w, l.w);
    const size_t o = (size_t)(p0 + pl) * 1024 + c0 + c4;
    *(ushort4*)(Th + o) = h;
    *(ushort4*)(Tl + o) = l;
}

// ---------------------------------------------------------------------------
// GEMM core v10: SINGLE-BARRIER counted-vmcnt pipeline, triple-buffered B.
// A loads via inline asm (invisible to compiler waitcnt pass).
// Step s: issue A(s+1) + D(s+2); vmcnt(N) retires A(s),D(s),D(s+1) keeping
// {A(s+1),D(s+2)}; ds_read B(s) + MFMA; s_barrier. One barrier per step.
// Tile 128 x (32*NJ), BK=32, 4 waves 2x2, wave 64 x (16*NJ) = 4xNJ MFMA tiles.
// TERMS=3: ah*bh + ah*bl + al*bh.  TERMS=2: ah*bh + ah*bl.
template<int TERMS, int NJ>
__device__ __forceinline__ void gemm_core(
    const unsigned short* __restrict__ Ah, const unsigned short* __restrict__ Al,
    const unsigned short* __restrict__ Bh, const unsigned short* __restrict__ Bl,
    int ldkB, int kpanA, int kbeg, int kend, int m0, int n0,
    unsigned short* Bs_h, unsigned short* Bs_l,   // each [3][32*NJ*32]
    f32x4 (&acc)[4][NJ])
{
    const int tid  = threadIdx.x;
    const int lane = tid & 63;
    const int wv   = tid >> 6;
    const int wm   = (wv >> 1) * 64;
    const int wn   = (wv & 1) * (16 * NJ);
    const int lr   = lane & 15;
    const int quad = lane >> 4;
    const int BUFE = 1024 * NJ;            // elems per h/l LDS buffer
    constexpr int AOPS = (TERMS == 3 ? 8 : 4);

    // --- B staging: waves {0,1} -> Bs_h, waves {2,3} -> Bs_l; NJ insts/wave ---
    const unsigned short* gsrc = (wv < 2) ? Bh : Bl;
    unsigned short* ldst = (wv < 2) ? Bs_h : Bs_l;
    const int tt0  = (wv & 1) * NJ;
    const int lrow = lane >> 2;
    const int gseg = ((lane & 3) - ((lane >> 3) & 3)) & 3;  // store-side swizzle
    const size_t bstep = (size_t)16 * (size_t)ldkB;         // 16 B-rows
    const unsigned short* gp0 =
        gsrc + (size_t)(n0 + tt0 * 16 + lrow) * ldkB + kbeg + gseg * 8;

    // --- A frag base: swizzled layout -> contiguous lane*16B loads ---
    const int pk0 = kbeg >> 5;
    const size_t astr  = (size_t)kpanA * 512;               // per 16-row panel
    const size_t abase = (size_t)((m0 + wm) >> 4) * astr + (size_t)pk0 * 512
                       + (size_t)lane * 8;
    const unsigned short* ap0 = Ah + abase;
    const unsigned short* al0 = (TERMS == 3) ? (Al + abase) : nullptr;

    const int rdseg = (quad + (lr >> 1)) & 3;               // LDS read-side swizzle

    const int nsteps = (kend - kbeg) >> 5;   // conv/final 32, logits 16 (even)

    // prologue (FIFO order matters): D(0)->buf0, A(0)->regs, D(1)->buf1;
    // vmcnt(AOPS+NJ) retires D(0); barrier makes it cross-wave visible.
#pragma unroll
    for (int u = 0; u < NJ; ++u)
        gld16(gp0 + (size_t)u * bstep, ldst + 0 * BUFE + (tt0 + u) * 512);

    bf16x8 cah[4], cal[4], nah[4], nal[4];
#pragma unroll
    for (int i = 0; i < 4; ++i) {
        cah[i] = gload16(ap0 + (size_t)i * astr);
        if (TERMS == 3) cal[i] = gload16(al0 + (size_t)i * astr);
    }
#pragma unroll
    for (int u = 0; u < NJ; ++u)
        gld16(gp0 + (size_t)u * bstep + 32, ldst + 1 * BUFE + (tt0 + u) * 512);

    vmwait<AOPS + NJ>();
    RAW_BARRIER();

    int br = 0;            // read buffer for current step  (s % 3)
    int bw = 2;            // write buffer for step s+2     ((s+2) % 3)

#define GSTEP(S, CH, CL, NH, NL)                                              \
    {                                                                         \
        const bool hasA = (S) + 1 < nsteps;                                   \
        const bool hasD = (S) + 2 < nsteps;                                   \
        if (hasA) {                                                           \
            const size_t aoff = (size_t)((S) + 1) * 512;                      \
            _Pragma("unroll")                                                 \
            for (int i = 0; i < 4; ++i) {                                     \
                NH[i] = gload16(ap0 + (size_t)i * astr + aoff);               \
                if (TERMS == 3)                                               \
                    NL[i] = gload16(al0 + (size_t)i * astr + aoff);           \
            }                                                                 \
        }                                                                     \
        if (hasD) {                                                           \
            const size_t goff = (size_t)((S) + 2) * 32;                       \
            unsigned short* dst = ldst + bw * BUFE;                           \
            _Pragma("unroll")                                                 \
            for (int u = 0; u < NJ; ++u)                                      \
                gld16(gp0 + (size_t)u * bstep + goff, dst + (tt0 + u) * 512); \
        }                                                                     \
        if (hasA && hasD) vmwait<AOPS + NJ>();                                \
        else if (hasA)    vmwait<AOPS>();                                     \
        else              vmwait<0>();                                        \
        __builtin_amdgcn_sched_barrier(0);                                    \
        const int rbase = br * BUFE + (wn + lr) * 32 + rdseg * 8;             \
        _Pragma("unroll")                                                     \
        for (int j = 0; j < NJ; ++j) {                                        \
            const bf16x8 bh = *(const bf16x8*)(Bs_h + rbase + j * 512);       \
            const bf16x8 bl = *(const bf16x8*)(Bs_l + rbase + j * 512);       \
            _Pragma("unroll")                                                 \
            for (int i = 0; i < 4; ++i) {                                     \
                acc[i][j] = __builtin_amdgcn_mfma_f32_16x16x32_bf16(          \
                    CH[i], bh, acc[i][j], 0, 0, 0);                           \
                acc[i][j] = __builtin_amdgcn_mfma_f32_16x16x32_bf16(          \
                    CH[i], bl, acc[i][j], 0, 0, 0);                           \
                if (TERMS == 3)                                               \
                    acc[i][j] = __builtin_amdgcn_mfma_f32_16x16x32_bf16(      \
                        CL[i], bh, acc[i][j], 0, 0, 0);                       \
            }                                                                 \
        }                                                                     \
        RAW_BARRIER();                                                        \
        br = (br == 2) ? 0 : br + 1;                                          \
        bw = (bw == 2) ? 0 : bw + 1;                                          \
    }

    for (int s = 0; s < nsteps; s += 2) {
        GSTEP(s,     cah, cal, nah, nal);
        GSTEP(s + 1, nah, nal, cah, cal);
    }
#undef GSTEP
    // Final GSTEP ends with a barrier -> LDS safely reusable by epilogues.
}

#define GEMM_PROLOGUE(NJ_)                                              \
    __shared__ __align__(16) unsigned short Bs_h[3 * 1024 * (NJ_)];     \
    __shared__ __align__(16) unsigned short Bs_l[3 * 1024 * (NJ_)];     \
    f32x4 acc[4][(NJ_)];                                                \
    _Pragma("unroll") for (int i = 0; i < 4; ++i)                       \
    _Pragma("unroll") for (int j = 0; j < (NJ_); ++j)                   \
    _Pragma("unroll") for (int r = 0; r < 4; ++r) acc[i][j][r] = 0.f;   \
    const int lane = threadIdx.x & 63;                                  \
    const int wv   = threadIdx.x >> 6;                                  \
    const int wm   = (wv >> 1) * 64;                                    \
    const int wn   = (wv & 1) * (16 * (NJ_));                           \
    const int lr   = lane & 15;                                         \
    const int quad = lane >> 4;                                         \
    (void)lane; (void)wv; (void)wm; (void)wn;

// ---------------------------------------------------------------------------
// ALL FOUR convs, one launch. 128x128 tiles (NJ=4). 640 blocks:
// mt (0..19) x nx (0..31); mt partitions [Wq(4) | Wk1(4) | Wk2(4) | Wv(8)].
// XCD-swizzled (640 % 8 == 0, bijective): XCD d owns wg in [80d, 80d+80).
// mode 2 (V conv) writes VT h/l DIRECTLY via LDS slab transpose (fused).
__global__ __launch_bounds__(256, 2) void conv_all_k(
    const unsigned short* __restrict__ Wqh, const unsigned short* __restrict__ Wql,
    const unsigned short* __restrict__ Wk1h, const unsigned short* __restrict__ Wk1l,
    const unsigned short* __restrict__ Wk2h, const unsigned short* __restrict__ Wk2l,
    const unsigned short* __restrict__ Wvh, const unsigned short* __restrict__ Wvl,
    const unsigned short* __restrict__ xmTh, const unsigned short* __restrict__ xmTl,
    const unsigned short* __restrict__ xfTh, const unsigned short* __restrict__ xfTl,
    const unsigned short* __restrict__ xlTh, const unsigned short* __restrict__ xlTl,
    const float* __restrict__ bq, const float* __restrict__ bk1,
    const float* __restrict__ bk2, const float* __restrict__ bv,
    unsigned short* __restrict__ Qh, unsigned short* __restrict__ Ql,
    unsigned short* __restrict__ Kfh, unsigned short* __restrict__ Kfl,
    unsigned short* __restrict__ Klh, unsigned short* __restrict__ Kll,
    unsigned short* __restrict__ VTh, unsigned short* __restrict__ VTl)
{
    GEMM_PROLOGUE(4);
    // XCD-aware bijective swizzle: XCD d owns wg in [80d, 80d+80)
    const int lid = blockIdx.y * 32 + blockIdx.x;        // 0..639
    const int wg  = (lid & 7) * 80 + (lid >> 3);
    const int mt  = wg >> 5;                             // 0..19
    const int n0  = (wg & 31) * 128;

    const unsigned short *Ah, *Al, *Bh, *Bl;
    const float* bias;
    unsigned short *Ch = nullptr, *Cl = nullptr;
    int mloc, mode;
    if (mt < 4) {
        Ah = Wqh;  Al = Wql;  Bh = xmTh; Bl = xmTl; bias = bq;
        Ch = Qh;   Cl = Ql;   mloc = mt * 128;        mode = 0;
    } else if (mt < 8) {
        Ah = Wk1h; Al = Wk1l; Bh = xfTh; Bl = xfTl; bias = bk1;
        Ch = Kfh;  Cl = Kfl;  mloc = (mt - 4) * 128;  mode = 1;
    } else if (mt < 12) {
        Ah = Wk2h; Al = Wk2l; Bh = xlTh; Bl = xlTl; bias = bk2;
        Ch = Klh;  Cl = Kll;  mloc = (mt - 8) * 128;  mode = 1;
    } else {
        Ah = Wvh;  Al = Wvl;  Bh = xmTh; Bl = xmTl; bias = bv;
        mloc = (mt - 12) * 128;                       mode = 2;
    }

    gemm_core<3, 4>(Ah, Al, Bh, Bl, 1024, 32, 0, 1024, mloc, n0, Bs_h, Bs_l, acc);

    if (mode == 2) {
        // Fused transpose: core ends with a barrier; extra sync is harmless.
        // Stage 32-pixel-row slabs [32][136] in dead B LDS, write VT[p][c]
        // h/l coalesced. Each thread owns 16 channels = TWO bf16x8 writes.
        __syncthreads();
        unsigned short (*Sh)[136] = (unsigned short (*)[136])Bs_h;
        unsigned short (*Sl)[136] = (unsigned short (*)[136])Bs_l;
        const int myhalf = (wv & 1);          // wn==64 waves own p_local>=64
#pragma unroll
        for (int sb = 0; sb < 4; ++sb) {
            if ((sb >> 1) == myhalf) {
                const int jbase = (sb & 1) * 2;
#pragma unroll
                for (int jj = 0; jj < 2; ++jj) {
                    const int j = jbase + jj;
                    const int prow = jj * 16 + lr;
#pragma unroll
                    for (int i = 0; i < 4; ++i) {
#pragma unroll
                        for (int r = 0; r < 4; ++r) {
                            const int c = wm + i * 16 + quad * 4 + r;
                            const float v = acc[i][j][r] + bias[mloc + c];
                            unsigned short h, l;
                            split2(v, h, l);
                            Sh[prow][c] = h;
                            Sl[prow][c] = l;
                        }
                    }
                }
            }
            __syncthreads();
            {
                const int pl2 = threadIdx.x >> 3;         // 0..31
                const int c0  = (threadIdx.x & 7) * 16;   // 0..112 (16-ch span)
                const size_t ob = (size_t)(n0 + sb * 32 + pl2) * 1024 + mloc + c0;
                *(bf16x8*)(VTh + ob)     = *(const bf16x8*)&Sh[pl2][c0];
                *(bf16x8*)(VTh + ob + 8) = *(const bf16x8*)&Sh[pl2][c0 + 8];
                *(bf16x8*)(VTl + ob)     = *(const bf16x8*)&Sl[pl2][c0];
                *(bf16x8*)(VTl + ob + 8) = *(const bf16x8*)&Sl[pl2][c0 + 8];
            }
            __syncthreads();
        }
        return;
    }

#pragma unroll
    for (int i = 0; i < 4; ++i) {
        const int mb = mloc + wm + i * 16 + quad * 4;
#pragma unroll
        for (int j = 0; j < 4; ++j) {
            const int nn = n0 + wn + j * 16 + lr;
#pragma unroll
            for (int r = 0; r < 4; ++r) {
                const float v = acc[i][j][r] + bias[mb + r];
                if (mode == 0) {
                    unsigned short h, l;
                    split2(v, h, l);
                    const size_t idx = (size_t)(mb + r) * 4096 + nn;
                    Ch[idx] = h;
                    Cl[idx] = l;
                } else {
                    // swizzled store for logits-A view [1024][2048]
                    const int m2 = ((mb + r) << 1) | (nn >> 11);
                    const int k2 = nn & 2047;
                    const size_t o = swz(m2, k2, 64);
                    unsigned short h, l;
                    split2(v, h, l);
                    Ch[o] = h;
                    Cl[o] = l;
                }
            }
        }
    }
}

// ---------------------------------------------------------------------------
// Fused logits, split-K, 128x128 tiles (NJ=4). 512 blocks:
// z = which(f/l)*4 + kslice(0..3), m-tile(0..7), n-tile(0..7).
// XCD-swizzled so each XCD owns one full z-slice (A 2MB + Q 2MB fit 4MB L2).
__global__ __launch_bounds__(256, 2) void logits_fused_k(
    const unsigned short* __restrict__ Kfh, const unsigned short* __restrict__ Kfl,
    const unsigned short* __restrict__ Klh, const unsigned short* __restrict__ Kll,
    const unsigned short* __restrict__ Qh, const unsigned short* __restrict__ Ql,
    float* __restrict__ Sfp, float* __restrict__ Slp)
{
    GEMM_PROLOGUE(4);
    const int lid = (blockIdx.z * 8 + blockIdx.y) * 8 + blockIdx.x;  // 0..511
    const int wg  = (lid & 7) * 64 + (lid >> 3);
    const int bx  = wg & 7;
    const int by  = (wg >> 3) & 7;
    const int bz  = wg >> 6;

    const int which = bz >> 2;
    const int slice = bz & 3;
    const unsigned short* Ah = which ? Klh : Kfh;
    const unsigned short* Al = which ? Kll : Kfl;
    float* out = (which ? Slp : Sfp) + (size_t)slice * 1024 * 1024;
    const int m0 = by * 128;
    const int n0 = bx * 128;

    gemm_core<3, 4>(Ah, Al, Qh, Ql, 2048, 64, slice * 512, slice * 512 + 512,
                    m0, n0, Bs_h, Bs_l, acc);

#pragma unroll
    for (int i = 0; i < 4; ++i) {
        const int mb = m0 + wm + i * 16 + quad * 4;
#pragma unroll
        for (int j = 0; j < 4; ++j) {
            const int nn = n0 + wn + j * 16 + lr;
#pragma unroll
            for (int r = 0; r < 4; ++r)
                out[(size_t)(mb + r) * 1024 + nn] = acc[i][j][r];
        }
    }
}

// ---------------------------------------------------------------------------
// Final: out = gamma*(A (x) VT) + 0.5*(xf+xl). A = Am swizzled (kpan=32),
// B = VT row-major ldk=1024. NJ=4, 256 blocks. 2-term.
__global__ __launch_bounds__(256, 2) void gemm_final_k(
    const unsigned short* __restrict__ Amh,
    const unsigned short* __restrict__ VTh, const unsigned short* __restrict__ VTl,
    float* __restrict__ out,
    const float* __restrict__ xf, const float* __restrict__ xl,
    const float* __restrict__ gamma)
{
    GEMM_PROLOGUE(4);
    const int m0 = blockIdx.y * 128;
    const int n0 = blockIdx.x * 128;

    gemm_core<2, 4>(Amh, nullptr, VTh, VTl, 1024, 32, 0, 1024, m0, n0,
                    Bs_h, Bs_l, acc);

    const float g = gamma[0];
#pragma unroll
    for (int i = 0; i < 4; ++i) {
        const int mb = m0 + wm + i * 16 + quad * 4;
#pragma unroll
        for (int j = 0; j < 4; ++j) {
            const int nn = n0 + wn + j * 16 + lr;
#pragma unroll
            for (int r = 0; r < 4; ++r) {
                const size_t idx = (size_t)(mb + r) * 4096 + nn;
                out[idx] = g * acc[i][j][r] + 0.5f * (xf[idx] + xl[idx]);
            }
        }
    }
}

// ---------------------------------------------------------------------------
// Row softmax over 4-slice partial sums: A = sm(sum Sfp) + sm(sum Slp),
// bf16 hi only (final GEMM is 2-term), stored SWIZZLED (kpan=32).
__global__ __launch_bounds__(256) void softmax_add4_k(
    const float* __restrict__ Sfp, const float* __restrict__ Slp,
    unsigned short* __restrict__ Ah)
{
    const int row = blockIdx.x;
    const int tid = threadIdx.x;
    __shared__ float red[8];
    const size_t base = (size_t)row * 1024 + tid * 4;
    const size_t SL = (size_t)1024 * 1024;

    float4 vf = *(const float4*)(Sfp + base);
    float4 vl = *(const float4*)(Slp + base);
#pragma unroll
    for (int s = 1; s < 4; ++s) {
        const float4 a = *(const float4*)(Sfp + s * SL + base);
        const float4 b = *(const float4*)(Slp + s * SL + base);
        vf.x += a.x; vf.y += a.y; vf.z += a.z; vf.w += a.w;
        vl.x += b.x; vl.y += b.y; vl.z += b.z; vl.w += b.w;
    }

    float mf = fmaxf(fmaxf(vf.x, vf.y), fmaxf(vf.z, vf.w));
    float ml = fmaxf(fmaxf(vl.x, vl.y), fmaxf(vl.z, vl.w));
#pragma unroll
    for (int off = 32; off; off >>= 1) {
        mf = fmaxf(mf, __shfl_down(mf, off, 64));
        ml = fmaxf(ml, __shfl_down(ml, off, 64));
    }
    const int wave = tid >> 6;
    if ((tid & 63) == 0) { red[wave] = mf; red[4 + wave] = ml; }
    __syncthreads();
    mf = fmaxf(fmaxf(red[0], red[1]), fmaxf(red[2], red[3]));
    ml = fmaxf(fmaxf(red[4], red[5]), fmaxf(red[6], red[7]));
    __syncthreads();

    const float4 ef = make_float4(expf(vf.x - mf), expf(vf.y - mf),
                                  expf(vf.z - mf), expf(vf.w - mf));
    const float4 el = make_float4(expf(vl.x - ml), expf(vl.y - ml),
                                  expf(vl.z - ml), expf(vl.w - ml));
    float sf = ef.x + ef.y + ef.z + ef.w;
    float sl = el.x + el.y + el.z + el.w;
#pragma unroll
    for (int off = 32; off; off >>= 1) {
        sf += __shfl_down(sf, off, 64);
        sl += __shfl_down(sl, off, 64);
    }
    if ((tid & 63) == 0) { red[wave] = sf; red[4 + wave] = sl; }
    __syncthreads();
    sf = red[0] + red[1] + red[2] + red[3];
    sl = red[4] + red[5] + red[6] + red[7];

    const float rf = 1.f / sf, rl = 1.f / sl;
    ushort4 h;
    h.x = f2bf(ef.x * rf + el.x * rl);
    h.y = f2bf(ef.y * rf + el.y * rl);
    h.z = f2bf(ef.z * rf + el.z * rl);
    h.w = f2bf(ef.w * rf + el.w * rl);
    const size_t o = swz(row, tid * 4, 32);   // 4 elems contiguous ((4t)&7 in {0,4})
    *(ushort4*)(Ah + o) = h;
}

__global__ void noop_k(float* p) { if (threadIdx.x == 1024) p[0] = 0.f; }

// ===========================================================================
extern "C" void kernel_launch(void* const* d_in, const int* in_sizes, int n_in,
                              void* d_out, int out_size, void* d_ws, size_t ws_size,
                              hipStream_t stream) {
    (void)in_sizes; (void)n_in; (void)out_size;
    const float* xf  = (const float*)d_in[0];
    const float* xm  = (const float*)d_in[1];
    const float* xl  = (const float*)d_in[2];
    const float* Wq  = (const float*)d_in[3];
    const float* bq  = (const float*)d_in[4];
    const float* Wk1 = (const float*)d_in[5];
    const float* bk1 = (const float*)d_in[6];
    const float* Wk2 = (const float*)d_in[7];
    const float* bk2 = (const float*)d_in[8];
    const float* Wv  = (const float*)d_in[9];
    const float* bv  = (const float*)d_in[10];
    const float* gamma = (const float*)d_in[11];
    float* out = (float*)d_out;

    const size_t MB = 1024 * 1024;
    if (ws_size < 98 * MB) {
        noop_k<<<dim3(1), dim3(64), 0, stream>>>((float*)d_ws);
        return;
    }

    // ---- workspace layout (byte offsets, 98 MB total) ----
    char* p = (char*)d_ws;
    unsigned short* xmT_h = (unsigned short*)(p + 0 * MB);    // [4096][1024] bf16, row-major
    unsigned short* xmT_l = (unsigned short*)(p + 8 * MB);
    unsigned short* xfT_h = (unsigned short*)(p + 16 * MB);
    unsigned short* xfT_l = (unsigned short*)(p + 24 * MB);
    unsigned short* xlT_h = (unsigned short*)(p + 32 * MB);
    unsigned short* xlT_l = (unsigned short*)(p + 40 * MB);
    unsigned short* Wq_h  = (unsigned short*)(p + 48 * MB);   // swizzled
    unsigned short* Wq_l  = (unsigned short*)(p + 49 * MB);
    unsigned short* Wk1_h = (unsigned short*)(p + 50 * MB);
    unsigned short* Wk1_l = (unsigned short*)(p + 51 * MB);
    unsigned short* Wk2_h = (unsigned short*)(p + 52 * MB);
    unsigned short* Wk2_l = (unsigned short*)(p + 53 * MB);
    unsigned short* Wv_h  = (unsigned short*)(p + 54 * MB);
    unsigned short* Wv_l  = (unsigned short*)(p + 56 * MB);
    unsigned short* Q_h   = (unsigned short*)(p + 58 * MB);   // row-major [1024][2048]
    unsigned short* Q_l   = (unsigned short*)(p + 62 * MB);
    unsigned short* Kf_h  = (unsigned short*)(p + 66 * MB);   // swizzled [1024][2048]
    unsigned short* Kf_l  = (unsigned short*)(p + 70 * MB);
    unsigned short* Kl_h  = (unsigned short*)(p + 74 * MB);
    unsigned short* Kl_l  = (unsigned short*)(p + 78 * MB);
    unsigned short* VT_h  = (unsigned short*)(p + 82 * MB);   // [4096][1024] bf16 (fused out of conv)
    unsigned short* VT_l  = (unsigned short*)(p + 90 * MB);
    // lifetime-based reuse (launch order: convs -> logits -> softmax -> final):
    float*          Sfp  = (float*)(p + 16 * MB);  // [4][1024][1024] over xfT (dead after convs)
    float*          Slp  = (float*)(p + 32 * MB);  // over xlT
    unsigned short* Am_h = (unsigned short*)(p + 74 * MB);  // swizzled, over Kl (dead after logits)

    const dim3 blk(256);
    // prep (2 launches): transpose+split the 3 inputs; split the 4 weights
    transpose3_k<<<dim3(128, 32, 3), blk, 0, stream>>>(
        xm, xf, xl, xmT_h, xmT_l, xfT_h, xfT_l, xlT_h, xlT_l);
    weights_split_k<<<dim3(2560), blk, 0, stream>>>(
        Wq, Wk1, Wk2, Wv, Wq_h, Wq_l, Wk1_h, Wk1_l, Wk2_h, Wk2_l, Wv_h, Wv_l);
    // ALL convs, one launch (640 blocks); V conv writes VT h/l directly
    conv_all_k<<<dim3(32, 20), blk, 0, stream>>>(
        Wq_h, Wq_l, Wk1_h, Wk1_l, Wk2_h, Wk2_l, Wv_h, Wv_l,
        xmT_h, xmT_l, xfT_h, xfT_l, xlT_h, xlT_l,
        bq, bk1, bk2, bv,
        Q_h, Q_l, Kf_h, Kf_l, Kl_h, Kl_l, VT_h, VT_l);
    // logits fused + split-K=4 (512 blocks, XCD z-sliced)
    logits_fused_k<<<dim3(8, 8, 8), blk, 0, stream>>>(
        Kf_h, Kf_l, Kl_h, Kl_l, Q_h, Q_l, Sfp, Slp);
    // A = softmax(sum Sfp) + softmax(sum Slp), swizzled bf16-hi over dead Kl
    softmax_add4_k<<<dim3(1024), blk, 0, stream>>>(Sfp, Slp, Am_h);
    // out = gamma*(A (x) VT) + (xf+xl)/2   (256 blocks)
    gemm_final_k<<<dim3(32, 8), blk, 0, stream>>>(
        Am_h, VT_h, VT_l, out, xf, xl, gamma);
}